// Round 1
// baseline (389.896 us; speedup 1.0000x reference)
//
#include <hip/hip_runtime.h>

// ---- sizes ----
// x: (128, 256, 28, 28) fp32.  b=16, t=8, c=256, h=w=28, p=4, ph=pw=7, e=4096.
// y1 (ws): [(b*8+t)][pp=ph*7+pw][e'], e' = c*16 + p1*4 + p2  (own permutation; LN/attn are e-permutation invariant)

#define IDX36(a,b) ((((a)*8)+(b))-((((a)*((a)+1)))/2))

__device__ __forceinline__ float wsum64(float v){
  #pragma unroll
  for (int off=32; off; off>>=1) v += __shfl_xor(v, off);
  return v;
}

// ---------------- temporal stage ----------------
// One block per sequence s=(b,ph,pw). Gram over 8 tokens -> per-thread redundant
// 8x8 softmax math -> fused recombination, writes Y1 in spatial-friendly layout.
__global__ __launch_bounds__(256) void k_temporal(const float* __restrict__ x, float* __restrict__ y1){
  const int s = blockIdx.x;              // 0..783
  const int b = s / 49, rem = s % 49, ph = rem / 7, pw = rem % 7;
  const int tid = threadIdx.x;
  const int cofs = tid >> 2;             // 0..63
  const int p1 = tid & 3;
  const int pixoff = (ph*4 + p1)*28 + pw*4;

  float Au[36], sm[8];
  #pragma unroll
  for (int i=0;i<36;i++) Au[i]=0.f;
  #pragma unroll
  for (int t=0;t<8;t++) sm[t]=0.f;

  #pragma unroll
  for (int k=0;k<4;k++){
    const int c = k*64 + cofs;
    float4 v[8];
    #pragma unroll
    for (int t=0;t<8;t++){
      const int addr = ((b*8+t)*256 + c)*784 + pixoff;
      v[t] = *reinterpret_cast<const float4*>(x + addr);
    }
    #pragma unroll
    for (int a=0;a<8;a++){
      sm[a] += v[a].x+v[a].y+v[a].z+v[a].w;
      #pragma unroll
      for (int b2=a;b2<8;b2++){
        Au[IDX36(a,b2)] += v[a].x*v[b2].x + v[a].y*v[b2].y + v[a].z*v[b2].z + v[a].w*v[b2].w;
      }
    }
  }
  #pragma unroll
  for (int i=0;i<36;i++) Au[i] = wsum64(Au[i]);
  #pragma unroll
  for (int t=0;t<8;t++) sm[t] = wsum64(sm[t]);

  __shared__ float red[44*4];
  const int wv = tid >> 6, lane = tid & 63;
  if (lane == 0){
    #pragma unroll
    for (int i=0;i<36;i++) red[i*4+wv] = Au[i];
    #pragma unroll
    for (int t=0;t<8;t++) red[(36+t)*4+wv] = sm[t];
  }
  __syncthreads();

  float Ar[36], mean[8], rstd[8];
  #pragma unroll
  for (int i=0;i<36;i++) Ar[i] = red[i*4]+red[i*4+1]+red[i*4+2]+red[i*4+3];
  #pragma unroll
  for (int t=0;t<8;t++){
    const float sv = red[(36+t)*4]+red[(36+t)*4+1]+red[(36+t)*4+2]+red[(36+t)*4+3];
    mean[t] = sv * (1.f/4096.f);
    const float var = Ar[IDX36(t,t)] * (1.f/4096.f) - mean[t]*mean[t];
    rstd[t] = rsqrtf(var + 1e-5f);
  }

  // G(a,b) = n_a . n_b  for a,b in [0,8], index 8 == zero token (shift pad)
  #define GV(a,b) ((((a)<8)&&((b)<8)) ? (rstd[(a)]*rstd[(b)]*(Ar[((a)<=(b))?IDX36((a),(b)):IDX36((b),(a))] - 4096.f*mean[(a)]*mean[(b)])) : 0.f)

  float Wm[8][8], cc[8];
  #pragma unroll
  for (int i=0;i<8;i++){
    float l[8]; float mx = -1e30f;
    #pragma unroll
    for (int j=0;j<8;j++){
      const float sij = GV(i+1,j+1) - GV(i+1,j) - GV(i,j+1) + GV(i,j);
      l[j] = sij * (1.f/64.f);
      mx = fmaxf(mx, l[j]);
    }
    float ss = 0.f;
    #pragma unroll
    for (int j=0;j<8;j++){ l[j] = __expf(l[j]-mx); ss += l[j]; }
    const float inv = 1.f/ss;
    cc[i] = 0.f;
    #pragma unroll
    for (int k2=0;k2<8;k2++){
      // out[i] = sum_j P[i,j]*(n[j+1]-n[j]) + y[i];  coefficient of n[k2]:
      float q = (((k2>=1)? l[k2-1] : 0.f) - l[k2]) * inv;
      const float wv2 = q * rstd[k2];
      Wm[i][k2] = wv2;
      cc[i] -= wv2 * mean[k2];
    }
  }
  #undef GV

  const int pp = ph*7 + pw;
  #pragma unroll
  for (int k=0;k<4;k++){
    const int c = k*64 + cofs;
    float4 v[8];
    #pragma unroll
    for (int t=0;t<8;t++){
      const int addr = ((b*8+t)*256 + c)*784 + pixoff;
      v[t] = *reinterpret_cast<const float4*>(x + addr);   // L3-resident re-read
    }
    #pragma unroll
    for (int i=0;i<8;i++){
      float4 o;
      o.x = v[i].x + cc[i]; o.y = v[i].y + cc[i]; o.z = v[i].z + cc[i]; o.w = v[i].w + cc[i];
      #pragma unroll
      for (int j=0;j<8;j++){
        o.x += Wm[i][j]*v[j].x; o.y += Wm[i][j]*v[j].y;
        o.z += Wm[i][j]*v[j].z; o.w += Wm[i][j]*v[j].w;
      }
      const int daddr = ((b*8+i)*49 + pp)*4096 + c*16 + p1*4;  // contiguous across wave
      *reinterpret_cast<float4*>(y1 + daddr) = o;
    }
  }
}

// ---------------- spatial stage: Gram partials ----------------
// grid = 128 bt * 4 K-slices. Padded 64x64 Gram GEMM over K=1024 slice.
// Row 49 = all-ones -> row sums come free. Rows 50..63 = zero.
__global__ __launch_bounds__(256) void k_s1(const float* __restrict__ y1, float* __restrict__ wsA){
  const int bt = blockIdx.x >> 2;
  const int slice = blockIdx.x & 3;
  const int tid = threadIdx.x;
  __shared__ float Tt[32][64];           // [e][j]
  const int jload = tid >> 2;            // 0..63
  const int el = (tid & 3) * 8;
  const int ty = tid >> 4, tx = tid & 15;
  float acc[4][4];
  #pragma unroll
  for (int i=0;i<4;i++){ acc[i][0]=0.f; acc[i][1]=0.f; acc[i][2]=0.f; acc[i][3]=0.f; }
  const float* yb = y1 + bt*49*4096 + slice*1024;

  for (int st=0; st<32; ++st){
    float vals[8];
    if (jload < 49){
      const float* p = yb + jload*4096 + st*32 + el;
      const float4 a  = *reinterpret_cast<const float4*>(p);
      const float4 b2 = *reinterpret_cast<const float4*>(p+4);
      vals[0]=a.x; vals[1]=a.y; vals[2]=a.z; vals[3]=a.w;
      vals[4]=b2.x; vals[5]=b2.y; vals[6]=b2.z; vals[7]=b2.w;
    } else {
      const float f = (jload == 49) ? 1.f : 0.f;
      #pragma unroll
      for (int l=0;l<8;l++) vals[l]=f;
    }
    __syncthreads();
    #pragma unroll
    for (int l=0;l<8;l++) Tt[el+l][jload] = vals[l];
    __syncthreads();
    #pragma unroll
    for (int e=0;e<32;e++){
      const float4 av = *reinterpret_cast<const float4*>(&Tt[e][ty*4]);
      const float4 bv = *reinterpret_cast<const float4*>(&Tt[e][tx*4]);
      const float aa[4] = {av.x,av.y,av.z,av.w};
      const float bb[4] = {bv.x,bv.y,bv.z,bv.w};
      #pragma unroll
      for (int i=0;i<4;i++){
        #pragma unroll
        for (int j=0;j<4;j++) acc[i][j] += aa[i]*bb[j];
      }
    }
  }
  float* wp = wsA + blockIdx.x * 2500;
  #pragma unroll
  for (int i=0;i<4;i++){
    const int gi = ty*4+i;
    if (gi < 50){
      #pragma unroll
      for (int j=0;j<4;j++){
        const int gj = tx*4+j;
        if (gj < 50) wp[gi*50+gj] = acc[i][j];
      }
    }
  }
}

// ---------------- spatial stage: softmax -> W, c ----------------
__global__ __launch_bounds__(256) void k_s2(const float* __restrict__ wsA, float* __restrict__ wsW, float* __restrict__ wsC){
  const int bt = blockIdx.x;
  const int tid = threadIdx.x;
  __shared__ float A[2500];
  __shared__ float m[49], r[49];
  for (int idx=tid; idx<2500; idx+=256){
    float v = 0.f;
    #pragma unroll
    for (int sl=0; sl<4; sl++) v += wsA[(bt*4+sl)*2500 + idx];
    A[idx] = v;
  }
  __syncthreads();
  if (tid < 49){
    const float mm = A[49*50+tid] * (1.f/4096.f);        // row 49 = ones row -> sums
    const float var = A[tid*50+tid] * (1.f/4096.f) - mm*mm;
    m[tid]=mm; r[tid]=rsqrtf(var+1e-5f);
  }
  __syncthreads();
  const int wv = tid>>6, lane = tid&63;
  for (int i=wv; i<49; i+=4){
    const float ri = r[i], mi = m[i];
    float rv=0.f, mv=0.f, L=-1e30f;
    if (lane < 49){
      rv = r[lane]; mv = m[lane];
      L = ri*rv*(A[i*50+lane] - 4096.f*mi*mv) * (1.f/64.f);
    }
    float mx = L;
    #pragma unroll
    for (int off=32; off; off>>=1) mx = fmaxf(mx, __shfl_xor(mx, off));
    const float p = (lane<49) ? __expf(L-mx) : 0.f;
    const float ss = wsum64(p);
    const float Wv = (p/ss)*rv;
    if (lane < 49) wsW[bt*2401 + i*49 + lane] = Wv;
    const float cp = wsum64(-Wv*mv);
    if (lane == 0) wsC[bt*49+i] = cp;
  }
}

// ---------------- spatial stage: recombine + scatter back to x layout ----------------
// grid = 128 bt * 8 e-chunks of 512; each thread owns e0 and e0+256 (49+49 accumulators).
__global__ __launch_bounds__(256) void k_s3(const float* __restrict__ y1, const float* __restrict__ wsW,
                                            const float* __restrict__ wsC, float* __restrict__ out){
  const int bt = blockIdx.x >> 3;
  const int chunk = blockIdx.x & 7;
  const int tid = threadIdx.x;
  __shared__ float Wl[2401];
  __shared__ float cl[49];
  for (int idx=tid; idx<2401; idx+=256)
    Wl[idx] = wsW[bt*2401+idx] + ((idx % 50 == 0) ? 1.f : 0.f);   // fold +I (residual)
  if (tid < 49) cl[tid] = wsC[bt*49+tid];
  __syncthreads();
  const int e0 = chunk*512 + tid;
  float acc0[49], acc1[49];
  #pragma unroll
  for (int i=0;i<49;i++){ acc0[i]=0.f; acc1[i]=0.f; }
  const float* yb = y1 + bt*49*4096;
  for (int j=0;j<49;++j){
    const float v0 = yb[j*4096 + e0];
    const float v1 = yb[j*4096 + e0 + 256];
    #pragma unroll
    for (int i=0;i<49;i++){
      const float wv2 = Wl[i*49+j];     // LDS broadcast
      acc0[i] += wv2*v0;
      acc1[i] += wv2*v1;
    }
  }
  const int c  = e0 >> 4;
  const int p1 = (e0 >> 2) & 3;
  const int p2 = e0 & 3;
  float* ob = out + bt*200704;
  const int ebase = c*784 + p1*28 + p2;
  #pragma unroll
  for (int i=0;i<49;i++){
    const int phh = i/7, pww = i%7;
    const int addr = ebase + phh*112 + pww*4;
    const float ci = cl[i];
    ob[addr]            = acc0[i] + ci;
    ob[addr + 16*784]   = acc1[i] + ci;   // e1 = e0+256 -> c+16
  }
}

extern "C" void kernel_launch(void* const* d_in, const int* in_sizes, int n_in,
                              void* d_out, int out_size, void* d_ws, size_t ws_size,
                              hipStream_t stream) {
  const float* x = (const float*)d_in[0];
  float* out = (float*)d_out;
  float* ws  = (float*)d_ws;
  float* y1  = ws;                      // 25,690,112 floats (102.8 MB)
  float* wsA = y1 + 25690112;           // 512*2500
  float* wsW = wsA + 512*2500;          // 128*2401
  float* wsC = wsW + 128*2401;          // 128*49   -> total ~109.2 MB
  hipLaunchKernelGGL(k_temporal, dim3(784),  dim3(256), 0, stream, x, y1);
  hipLaunchKernelGGL(k_s1,       dim3(512),  dim3(256), 0, stream, y1, wsA);
  hipLaunchKernelGGL(k_s2,       dim3(128),  dim3(256), 0, stream, wsA, wsW, wsC);
  hipLaunchKernelGGL(k_s3,       dim3(1024), dim3(256), 0, stream, y1, wsW, wsC, out);
}

// Round 2
// 244.809 us; speedup vs baseline: 1.5927x; 1.5927x over previous
//
#include <hip/hip_runtime.h>

// x: (128, 256, 28, 28) fp32.  b=16, t=8, c=256, h=w=28, p=4, ph=pw=7, e=4096.
// y1 (ws): [bt][pp][e'], e' = c*16 + p1*4 + p2 (LN/attn are e-permutation invariant).

#define IDX36(a,b) ((((a)*8)+(b))-((((a)*((a)+1)))/2))

__device__ __forceinline__ float wsum64(float v){
  #pragma unroll
  for (int off=32; off; off>>=1) v += __shfl_xor(v, off);
  return v;
}
__device__ __forceinline__ float wsum32(float v){
  #pragma unroll
  for (int off=16; off; off>>=1) v += __shfl_xor(v, off);
  return v;
}

// ---------------- temporal stage 1: partial Grams per c-slice ----------------
// grid = 16b * 7ph * 16slice. Stage 8t x 16c x (4 rows x 28 cols) stripe in LDS
// (coalesced 448B segments), compute per-patch Gram partials from LDS.
__global__ __launch_bounds__(256) void k_t1(const float* __restrict__ x, float* __restrict__ wsG){
  const int bx = blockIdx.x;
  const int b = bx / 112;
  const int ph = (bx % 112) / 16;
  const int slice = bx & 15;
  const int c0 = slice * 16;
  const int tid = threadIdx.x;

  __shared__ float lds[8*16*116];   // [t][c][116-padded stripe of 112 floats]
  const float4* x4 = reinterpret_cast<const float4*>(x);

  #pragma unroll
  for (int t=0;t<8;t++){
    const int base = ((b*8+t)*256 + c0)*196 + ph*28;
    {
      const int f = tid, c = f/28, m = f%28;
      *reinterpret_cast<float4*>(&lds[(t*16+c)*116 + m*4]) = x4[base + c*196 + m];
    }
    if (tid < 192){
      const int f = 256+tid, c = f/28, m = f%28;
      *reinterpret_cast<float4*>(&lds[(t*16+c)*116 + m*4]) = x4[base + c*196 + m];
    }
  }
  __syncthreads();

  const int pw   = tid >> 5;        // 0..6 valid; group 7 is idle-compute
  const int slot = tid & 31;
  const int c    = slot >> 1;
  const int p1b  = (slot & 1) * 2;

  float v[8][8];
  #pragma unroll
  for (int t=0;t<8;t++){
    const float* p = &lds[(t*16+c)*116 + p1b*28 + pw*4];
    const float4 a  = *reinterpret_cast<const float4*>(p);
    const float4 b2 = *reinterpret_cast<const float4*>(p + 28);
    v[t][0]=a.x;  v[t][1]=a.y;  v[t][2]=a.z;  v[t][3]=a.w;
    v[t][4]=b2.x; v[t][5]=b2.y; v[t][6]=b2.z; v[t][7]=b2.w;
  }

  float Au[36], sm[8];
  #pragma unroll
  for (int a2=0;a2<8;a2++){
    float s0 = 0.f;
    #pragma unroll
    for (int e=0;e<8;e++) s0 += v[a2][e];
    sm[a2] = s0;
    #pragma unroll
    for (int b2=a2;b2<8;b2++){
      float s = 0.f;
      #pragma unroll
      for (int e=0;e<8;e++) s += v[a2][e]*v[b2][e];
      Au[IDX36(a2,b2)] = s;
    }
  }
  #pragma unroll
  for (int i=0;i<36;i++) Au[i] = wsum32(Au[i]);
  #pragma unroll
  for (int t=0;t<8;t++) sm[t] = wsum32(sm[t]);

  if (slot == 0 && pw < 7){
    const int base = ((b*49 + ph*7 + pw)*16 + slice)*44;
    #pragma unroll
    for (int i=0;i<36;i++) wsG[base+i] = Au[i];
    #pragma unroll
    for (int t=0;t<8;t++)  wsG[base+36+t] = sm[t];
  }
}

// ---------------- temporal stage 2: reduce slices, softmax -> W, cc ----------------
__global__ __launch_bounds__(64) void k_t2(const float* __restrict__ wsG, float* __restrict__ wsWt){
  const int seq = blockIdx.x;
  const int lane = threadIdx.x;
  __shared__ float red[44];
  if (lane < 44){
    float a = 0.f;
    #pragma unroll
    for (int s=0;s<16;s++) a += wsG[(seq*16+s)*44 + lane];
    red[lane] = a;
  }
  __syncthreads();
  if (lane < 8){
    const int i = lane;
    float Ar[36], mean[8], rstd[8];
    #pragma unroll
    for (int k=0;k<36;k++) Ar[k] = red[k];
    #pragma unroll
    for (int t=0;t<8;t++){
      const float sv = red[36+t];
      mean[t] = sv * (1.f/4096.f);
      const float var = Ar[IDX36(t,t)] * (1.f/4096.f) - mean[t]*mean[t];
      rstd[t] = rsqrtf(var + 1e-5f);
    }
    #define GV(a,b) ((((a)<8)&&((b)<8)) ? (rstd[(a)]*rstd[(b)]*(Ar[((a)<=(b))?IDX36((a),(b)):IDX36((b),(a))] - 4096.f*mean[(a)]*mean[(b)])) : 0.f)
    float l[8]; float mx = -1e30f;
    #pragma unroll
    for (int j=0;j<8;j++){
      const float sij = GV(i+1,j+1) - GV(i+1,j) - GV(i,j+1) + GV(i,j);
      l[j] = sij * (1.f/64.f);
      mx = fmaxf(mx, l[j]);
    }
    float ss = 0.f;
    #pragma unroll
    for (int j=0;j<8;j++){ l[j] = __expf(l[j]-mx); ss += l[j]; }
    const float inv = 1.f/ss;
    float cc = 0.f;
    #pragma unroll
    for (int k2=0;k2<8;k2++){
      const float q = (((k2>=1)? l[k2-1] : 0.f) - l[k2]) * inv;
      const float wv2 = q * rstd[k2];
      wsWt[seq*72 + i*8 + k2] = wv2;
      cc -= wv2 * mean[k2];
    }
    wsWt[seq*72 + 64 + i] = cc;
    #undef GV
  }
}

// ---------------- temporal stage 3: recombine + write y1 ----------------
// Coalesced direct re-read of x (L3-resident): lane index walks the contiguous
// stripe; each float4 belongs to exactly one patch (pw = m%7), W applied per-lane.
__global__ __launch_bounds__(256) void k_t3(const float* __restrict__ x, const float* __restrict__ wsWt,
                                            float* __restrict__ y1){
  const int bx = blockIdx.x;
  const int b = bx / 112;
  const int ph = (bx % 112) / 16;
  const int slice = bx & 15;
  const int c0 = slice * 16;
  const int tid = threadIdx.x;

  __shared__ float Wl[7][72];
  for (int idx=tid; idx<504; idx+=256)
    Wl[idx/72][idx%72] = wsWt[(b*49 + ph*7 + idx/72)*72 + idx%72];
  __syncthreads();

  const float4* x4 = reinterpret_cast<const float4*>(x);
  float4* y4 = reinterpret_cast<float4*>(y1);

  #pragma unroll
  for (int fi=0; fi<2; fi++){
    const int f = fi*256 + tid;
    if (f < 448){
      const int c = f/28, m = f%28, pw = m%7, p1 = m/7;
      float4 v[8];
      #pragma unroll
      for (int t=0;t<8;t++) v[t] = x4[((b*8+t)*256 + c0+c)*196 + ph*28 + m];
      const float* W = Wl[pw];
      const int pp = ph*7 + pw;
      #pragma unroll
      for (int i=0;i<8;i++){
        const float ci = W[64+i];
        float4 o;
        o.x = v[i].x + ci; o.y = v[i].y + ci; o.z = v[i].z + ci; o.w = v[i].w + ci;
        #pragma unroll
        for (int j=0;j<8;j++){
          const float w = W[i*8+j];
          o.x += w*v[j].x; o.y += w*v[j].y; o.z += w*v[j].z; o.w += w*v[j].w;
        }
        y4[((b*8+i)*49 + pp)*1024 + (c0+c)*4 + p1] = o;
      }
    }
  }
}

// ---------------- spatial stage: Gram partials ----------------
__global__ __launch_bounds__(256) void k_s1(const float* __restrict__ y1, float* __restrict__ wsA){
  const int bt = blockIdx.x >> 2;
  const int slice = blockIdx.x & 3;
  const int tid = threadIdx.x;
  __shared__ float Tt[32][64];           // [e][j]
  const int jload = tid >> 2;            // 0..63
  const int el = (tid & 3) * 8;
  const int ty = tid >> 4, tx = tid & 15;
  float acc[4][4];
  #pragma unroll
  for (int i=0;i<4;i++){ acc[i][0]=0.f; acc[i][1]=0.f; acc[i][2]=0.f; acc[i][3]=0.f; }
  const float* yb = y1 + bt*49*4096 + slice*1024;

  for (int st=0; st<32; ++st){
    float vals[8];
    if (jload < 49){
      const float* p = yb + jload*4096 + st*32 + el;
      const float4 a  = *reinterpret_cast<const float4*>(p);
      const float4 b2 = *reinterpret_cast<const float4*>(p+4);
      vals[0]=a.x; vals[1]=a.y; vals[2]=a.z; vals[3]=a.w;
      vals[4]=b2.x; vals[5]=b2.y; vals[6]=b2.z; vals[7]=b2.w;
    } else {
      const float f = (jload == 49) ? 1.f : 0.f;
      #pragma unroll
      for (int l=0;l<8;l++) vals[l]=f;
    }
    __syncthreads();
    #pragma unroll
    for (int l=0;l<8;l++) Tt[el+l][jload] = vals[l];
    __syncthreads();
    #pragma unroll
    for (int e=0;e<32;e++){
      const float4 av = *reinterpret_cast<const float4*>(&Tt[e][ty*4]);
      const float4 bv = *reinterpret_cast<const float4*>(&Tt[e][tx*4]);
      const float aa[4] = {av.x,av.y,av.z,av.w};
      const float bb[4] = {bv.x,bv.y,bv.z,bv.w};
      #pragma unroll
      for (int i=0;i<4;i++){
        #pragma unroll
        for (int j=0;j<4;j++) acc[i][j] += aa[i]*bb[j];
      }
    }
  }
  float* wp = wsA + blockIdx.x * 2500;
  #pragma unroll
  for (int i=0;i<4;i++){
    const int gi = ty*4+i;
    if (gi < 50){
      #pragma unroll
      for (int j=0;j<4;j++){
        const int gj = tx*4+j;
        if (gj < 50) wp[gi*50+gj] = acc[i][j];
      }
    }
  }
}

// ---------------- spatial stage: softmax -> W, c ----------------
__global__ __launch_bounds__(256) void k_s2(const float* __restrict__ wsA, float* __restrict__ wsW, float* __restrict__ wsC){
  const int bt = blockIdx.x;
  const int tid = threadIdx.x;
  __shared__ float A[2500];
  __shared__ float m[49], r[49];
  for (int idx=tid; idx<2500; idx+=256){
    float v = 0.f;
    #pragma unroll
    for (int sl=0; sl<4; sl++) v += wsA[(bt*4+sl)*2500 + idx];
    A[idx] = v;
  }
  __syncthreads();
  if (tid < 49){
    const float mm = A[49*50+tid] * (1.f/4096.f);        // row 49 = ones row -> sums
    const float var = A[tid*50+tid] * (1.f/4096.f) - mm*mm;
    m[tid]=mm; r[tid]=rsqrtf(var+1e-5f);
  }
  __syncthreads();
  const int wv = tid>>6, lane = tid&63;
  for (int i=wv; i<49; i+=4){
    const float ri = r[i], mi = m[i];
    float rv=0.f, mv=0.f, L=-1e30f;
    if (lane < 49){
      rv = r[lane]; mv = m[lane];
      L = ri*rv*(A[i*50+lane] - 4096.f*mi*mv) * (1.f/64.f);
    }
    float mx = L;
    #pragma unroll
    for (int off=32; off; off>>=1) mx = fmaxf(mx, __shfl_xor(mx, off));
    const float p = (lane<49) ? __expf(L-mx) : 0.f;
    const float ss = wsum64(p);
    const float Wv = (p/ss)*rv;
    if (lane < 49) wsW[bt*2401 + i*49 + lane] = Wv;
    const float cp = wsum64(-Wv*mv);
    if (lane == 0) wsC[bt*49+i] = cp;
  }
}

// ---------------- spatial stage: recombine + scatter back to x layout ----------------
__global__ __launch_bounds__(256) void k_s3(const float* __restrict__ y1, const float* __restrict__ wsW,
                                            const float* __restrict__ wsC, float* __restrict__ out){
  const int bt = blockIdx.x >> 3;
  const int chunk = blockIdx.x & 7;
  const int tid = threadIdx.x;
  __shared__ float Wl[2401];
  __shared__ float cl[49];
  for (int idx=tid; idx<2401; idx+=256)
    Wl[idx] = wsW[bt*2401+idx] + ((idx % 50 == 0) ? 1.f : 0.f);   // fold +I (residual)
  if (tid < 49) cl[tid] = wsC[bt*49+tid];
  __syncthreads();
  const int e0 = chunk*512 + tid;
  float acc0[49], acc1[49];
  #pragma unroll
  for (int i=0;i<49;i++){ acc0[i]=0.f; acc1[i]=0.f; }
  const float* yb = y1 + bt*49*4096;
  for (int j=0;j<49;++j){
    const float v0 = yb[j*4096 + e0];
    const float v1 = yb[j*4096 + e0 + 256];
    #pragma unroll
    for (int i=0;i<49;i++){
      const float wv2 = Wl[i*49+j];     // LDS broadcast
      acc0[i] += wv2*v0;
      acc1[i] += wv2*v1;
    }
  }
  const int c  = e0 >> 4;
  const int p1 = (e0 >> 2) & 3;
  const int p2 = e0 & 3;
  float* ob = out + bt*200704;
  const int ebase = c*784 + p1*28 + p2;
  #pragma unroll
  for (int i=0;i<49;i++){
    const int phh = i/7, pww = i%7;
    const int addr = ebase + phh*112 + pww*4;
    const float ci = cl[i];
    ob[addr]            = acc0[i] + ci;
    ob[addr + 16*784]   = acc1[i] + ci;   // e1 = e0+256 -> c+16
  }
}

extern "C" void kernel_launch(void* const* d_in, const int* in_sizes, int n_in,
                              void* d_out, int out_size, void* d_ws, size_t ws_size,
                              hipStream_t stream) {
  const float* x = (const float*)d_in[0];
  float* out = (float*)d_out;
  float* ws  = (float*)d_ws;
  float* y1  = ws;                      // 25,690,112 floats (102.8 MB)
  float* wsA = y1 + 25690112;           // 512*2500 = 1,280,000 floats
  float* wsW = wsA + 512*2500;          // 128*2401
  float* wsC = wsW + 128*2401;          // 128*49
  // overlay (dead before k_s1 writes wsA): temporal partials + per-seq W
  float* wsG  = wsA;                    // 784*16*44 = 551,936 floats
  float* wsWt = wsA + 551936;           // 784*72   =  56,448 floats (fits in wsA)
  hipLaunchKernelGGL(k_t1, dim3(1792), dim3(256), 0, stream, x, wsG);
  hipLaunchKernelGGL(k_t2, dim3(784),  dim3(64),  0, stream, wsG, wsWt);
  hipLaunchKernelGGL(k_t3, dim3(1792), dim3(256), 0, stream, x, wsWt, y1);
  hipLaunchKernelGGL(k_s1, dim3(512),  dim3(256), 0, stream, y1, wsA);
  hipLaunchKernelGGL(k_s2, dim3(128),  dim3(256), 0, stream, wsA, wsW, wsC);
  hipLaunchKernelGGL(k_s3, dim3(1024), dim3(256), 0, stream, y1, wsW, wsC, out);
}

// Round 3
// 235.130 us; speedup vs baseline: 1.6582x; 1.0412x over previous
//
#include <hip/hip_runtime.h>

// x: (128, 256, 28, 28) fp32.  b=16, t=8, c=256, h=w=28, p=4, ph=pw=7, e=4096.
// y1 (ws): [bt][pp][e'], e' = c*16 + p1*4 + p2 (LN/attn are e-permutation invariant).

#define IDX36(a,b) ((((a)*8)+(b))-((((a)*((a)+1)))/2))

__device__ __forceinline__ float wsum64(float v){
  #pragma unroll
  for (int off=32; off; off>>=1) v += __shfl_xor(v, off);
  return v;
}
__device__ __forceinline__ float wsum32(float v){
  #pragma unroll
  for (int off=16; off; off>>=1) v += __shfl_xor(v, off);
  return v;
}

// ---------------- temporal stage 1: partial Grams per c-slice ----------------
__global__ __launch_bounds__(256) void k_t1(const float* __restrict__ x, float* __restrict__ wsG){
  const int bx = blockIdx.x;
  const int b = bx / 112;
  const int ph = (bx % 112) / 16;
  const int slice = bx & 15;
  const int c0 = slice * 16;
  const int tid = threadIdx.x;

  __shared__ float lds[8*16*116];   // [t][c][116-padded stripe of 112 floats]
  const float4* x4 = reinterpret_cast<const float4*>(x);

  #pragma unroll
  for (int t=0;t<8;t++){
    const int base = ((b*8+t)*256 + c0)*196 + ph*28;
    {
      const int f = tid, c = f/28, m = f%28;
      *reinterpret_cast<float4*>(&lds[(t*16+c)*116 + m*4]) = x4[base + c*196 + m];
    }
    if (tid < 192){
      const int f = 256+tid, c = f/28, m = f%28;
      *reinterpret_cast<float4*>(&lds[(t*16+c)*116 + m*4]) = x4[base + c*196 + m];
    }
  }
  __syncthreads();

  const int pw   = tid >> 5;        // 0..6 valid; group 7 is idle-compute
  const int slot = tid & 31;
  const int c    = slot >> 1;
  const int p1b  = (slot & 1) * 2;

  float v[8][8];
  #pragma unroll
  for (int t=0;t<8;t++){
    const float* p = &lds[(t*16+c)*116 + p1b*28 + pw*4];
    const float4 a  = *reinterpret_cast<const float4*>(p);
    const float4 b2 = *reinterpret_cast<const float4*>(p + 28);
    v[t][0]=a.x;  v[t][1]=a.y;  v[t][2]=a.z;  v[t][3]=a.w;
    v[t][4]=b2.x; v[t][5]=b2.y; v[t][6]=b2.z; v[t][7]=b2.w;
  }

  float Au[36], sm[8];
  #pragma unroll
  for (int a2=0;a2<8;a2++){
    float s0 = 0.f;
    #pragma unroll
    for (int e=0;e<8;e++) s0 += v[a2][e];
    sm[a2] = s0;
    #pragma unroll
    for (int b2=a2;b2<8;b2++){
      float s = 0.f;
      #pragma unroll
      for (int e=0;e<8;e++) s += v[a2][e]*v[b2][e];
      Au[IDX36(a2,b2)] = s;
    }
  }
  #pragma unroll
  for (int i=0;i<36;i++) Au[i] = wsum32(Au[i]);
  #pragma unroll
  for (int t=0;t<8;t++) sm[t] = wsum32(sm[t]);

  if (slot == 0 && pw < 7){
    const int base = ((b*49 + ph*7 + pw)*16 + slice)*44;
    #pragma unroll
    for (int i=0;i<36;i++) wsG[base+i] = Au[i];
    #pragma unroll
    for (int t=0;t<8;t++)  wsG[base+36+t] = sm[t];
  }
}

// ---------------- temporal stage 2: reduce slices, softmax -> W, cc ----------------
__global__ __launch_bounds__(64) void k_t2(const float* __restrict__ wsG, float* __restrict__ wsWt){
  const int seq = blockIdx.x;
  const int lane = threadIdx.x;
  __shared__ float red[44];
  if (lane < 44){
    float a = 0.f;
    #pragma unroll
    for (int s=0;s<16;s++) a += wsG[(seq*16+s)*44 + lane];
    red[lane] = a;
  }
  __syncthreads();
  if (lane < 8){
    const int i = lane;
    float Ar[36], mean[8], rstd[8];
    #pragma unroll
    for (int k=0;k<36;k++) Ar[k] = red[k];
    #pragma unroll
    for (int t=0;t<8;t++){
      const float sv = red[36+t];
      mean[t] = sv * (1.f/4096.f);
      const float var = Ar[IDX36(t,t)] * (1.f/4096.f) - mean[t]*mean[t];
      rstd[t] = rsqrtf(var + 1e-5f);
    }
    #define GV(a,b) ((((a)<8)&&((b)<8)) ? (rstd[(a)]*rstd[(b)]*(Ar[((a)<=(b))?IDX36((a),(b)):IDX36((b),(a))] - 4096.f*mean[(a)]*mean[(b)])) : 0.f)
    float l[8]; float mx = -1e30f;
    #pragma unroll
    for (int j=0;j<8;j++){
      const float sij = GV(i+1,j+1) - GV(i+1,j) - GV(i,j+1) + GV(i,j);
      l[j] = sij * (1.f/64.f);
      mx = fmaxf(mx, l[j]);
    }
    float ss = 0.f;
    #pragma unroll
    for (int j=0;j<8;j++){ l[j] = __expf(l[j]-mx); ss += l[j]; }
    const float inv = 1.f/ss;
    float cc = 0.f;
    #pragma unroll
    for (int k2=0;k2<8;k2++){
      const float q = (((k2>=1)? l[k2-1] : 0.f) - l[k2]) * inv;
      const float wv2 = q * rstd[k2];
      wsWt[seq*72 + i*8 + k2] = wv2;
      cc -= wv2 * mean[k2];
    }
    wsWt[seq*72 + 64 + i] = cc;
    #undef GV
  }
}

// ---------------- temporal stage 3: recombine + write y1 ----------------
__global__ __launch_bounds__(256) void k_t3(const float* __restrict__ x, const float* __restrict__ wsWt,
                                            float* __restrict__ y1){
  const int bx = blockIdx.x;
  const int b = bx / 112;
  const int ph = (bx % 112) / 16;
  const int slice = bx & 15;
  const int c0 = slice * 16;
  const int tid = threadIdx.x;

  __shared__ float Wl[7][72];
  for (int idx=tid; idx<504; idx+=256)
    Wl[idx/72][idx%72] = wsWt[(b*49 + ph*7 + idx/72)*72 + idx%72];
  __syncthreads();

  const float4* x4 = reinterpret_cast<const float4*>(x);
  float4* y4 = reinterpret_cast<float4*>(y1);

  #pragma unroll
  for (int fi=0; fi<2; fi++){
    const int f = fi*256 + tid;
    if (f < 448){
      const int c = f/28, m = f%28, pw = m%7, p1 = m/7;
      float4 v[8];
      #pragma unroll
      for (int t=0;t<8;t++) v[t] = x4[((b*8+t)*256 + c0+c)*196 + ph*28 + m];
      const float* W = Wl[pw];
      const int pp = ph*7 + pw;
      #pragma unroll
      for (int i=0;i<8;i++){
        const float ci = W[64+i];
        float4 o;
        o.x = v[i].x + ci; o.y = v[i].y + ci; o.z = v[i].z + ci; o.w = v[i].w + ci;
        #pragma unroll
        for (int j=0;j<8;j++){
          const float w = W[i*8+j];
          o.x += w*v[j].x; o.y += w*v[j].y; o.z += w*v[j].z; o.w += w*v[j].w;
        }
        y4[((b*8+i)*49 + pp)*1024 + (c0+c)*4 + p1] = o;
      }
    }
  }
}

// ---------------- spatial stage: Gram partials ----------------
__global__ __launch_bounds__(256) void k_s1(const float* __restrict__ y1, float* __restrict__ wsA){
  const int bt = blockIdx.x >> 2;
  const int slice = blockIdx.x & 3;
  const int tid = threadIdx.x;
  __shared__ float Tt[32][64];           // [e][j]
  const int jload = tid >> 2;            // 0..63
  const int el = (tid & 3) * 8;
  const int ty = tid >> 4, tx = tid & 15;
  float acc[4][4];
  #pragma unroll
  for (int i=0;i<4;i++){ acc[i][0]=0.f; acc[i][1]=0.f; acc[i][2]=0.f; acc[i][3]=0.f; }
  const float* yb = y1 + bt*49*4096 + slice*1024;

  for (int st=0; st<32; ++st){
    float vals[8];
    if (jload < 49){
      const float* p = yb + jload*4096 + st*32 + el;
      const float4 a  = *reinterpret_cast<const float4*>(p);
      const float4 b2 = *reinterpret_cast<const float4*>(p+4);
      vals[0]=a.x; vals[1]=a.y; vals[2]=a.z; vals[3]=a.w;
      vals[4]=b2.x; vals[5]=b2.y; vals[6]=b2.z; vals[7]=b2.w;
    } else {
      const float f = (jload == 49) ? 1.f : 0.f;
      #pragma unroll
      for (int l=0;l<8;l++) vals[l]=f;
    }
    __syncthreads();
    #pragma unroll
    for (int l=0;l<8;l++) Tt[el+l][jload] = vals[l];
    __syncthreads();
    #pragma unroll
    for (int e=0;e<32;e++){
      const float4 av = *reinterpret_cast<const float4*>(&Tt[e][ty*4]);
      const float4 bv = *reinterpret_cast<const float4*>(&Tt[e][tx*4]);
      const float aa[4] = {av.x,av.y,av.z,av.w};
      const float bb[4] = {bv.x,bv.y,bv.z,bv.w};
      #pragma unroll
      for (int i=0;i<4;i++){
        #pragma unroll
        for (int j=0;j<4;j++) acc[i][j] += aa[i]*bb[j];
      }
    }
  }
  float* wp = wsA + blockIdx.x * 2500;
  #pragma unroll
  for (int i=0;i<4;i++){
    const int gi = ty*4+i;
    if (gi < 50){
      #pragma unroll
      for (int j=0;j<4;j++){
        const int gj = tx*4+j;
        if (gj < 50) wp[gi*50+gj] = acc[i][j];
      }
    }
  }
}

// ---------------- spatial stage: softmax -> WT (+I folded, padded 52), c ----------------
__global__ __launch_bounds__(256) void k_s2(const float* __restrict__ wsA, float* __restrict__ wsWT, float* __restrict__ wsC){
  const int bt = blockIdx.x;
  const int tid = threadIdx.x;
  __shared__ float A[2500];
  __shared__ float m[49], r[49];
  // zero the padded WT block (cols 49..51 of each row) for hygiene
  for (int idx=tid; idx<2548; idx+=256) wsWT[bt*2548+idx] = 0.f;
  for (int idx=tid; idx<2500; idx+=256){
    float v = 0.f;
    #pragma unroll
    for (int sl=0; sl<4; sl++) v += wsA[(bt*4+sl)*2500 + idx];
    A[idx] = v;
  }
  __syncthreads();
  if (tid < 49){
    const float mm = A[49*50+tid] * (1.f/4096.f);        // row 49 = ones row -> sums
    const float var = A[tid*50+tid] * (1.f/4096.f) - mm*mm;
    m[tid]=mm; r[tid]=rsqrtf(var+1e-5f);
  }
  __syncthreads();
  const int wv = tid>>6, lane = tid&63;
  for (int i=wv; i<49; i+=4){
    const float ri = r[i], mi = m[i];
    float rv=0.f, mv=0.f, L=-1e30f;
    if (lane < 49){
      rv = r[lane]; mv = m[lane];
      L = ri*rv*(A[i*50+lane] - 4096.f*mi*mv) * (1.f/64.f);
    }
    float mx = L;
    #pragma unroll
    for (int off=32; off; off>>=1) mx = fmaxf(mx, __shfl_xor(mx, off));
    const float p = (lane<49) ? __expf(L-mx) : 0.f;
    const float ss = wsum64(p);
    const float Wv = (p/ss)*rv;
    // WT[j=lane][i] = W[i][j] + I
    if (lane < 49) wsWT[bt*2548 + lane*52 + i] = Wv + ((lane==i) ? 1.f : 0.f);
    const float cp = wsum64(-Wv*mv);
    if (lane == 0) wsC[bt*49+i] = cp;
  }
}

// ---------------- spatial stage: recombine + scatter back to x layout ----------------
// 512 blocks = 128 bt * 4 e-chunks of 1024; each thread owns a float4 of e.
// W^T in LDS read as b128 broadcasts (13 per j); 49 float4 accumulators in VGPRs.
__global__ __launch_bounds__(256,2) void k_s3(const float* __restrict__ y1, const float* __restrict__ wsWT,
                                              const float* __restrict__ wsC, float* __restrict__ out){
  const int bt = blockIdx.x >> 2;
  const int chunk = blockIdx.x & 3;
  const int tid = threadIdx.x;
  __shared__ float WT[49*52];
  __shared__ float cl[49];
  for (int idx=tid; idx<2548; idx+=256) WT[idx] = wsWT[bt*2548+idx];
  if (tid < 49) cl[tid] = wsC[bt*49+tid];
  __syncthreads();

  const int e0 = chunk*1024 + tid*4;
  float4 acc[49];
  #pragma unroll
  for (int i=0;i<49;i++){ acc[i].x=0.f; acc[i].y=0.f; acc[i].z=0.f; acc[i].w=0.f; }
  const float* yb = y1 + bt*49*4096;

  for (int j=0;j<49;++j){
    const float4 v = *reinterpret_cast<const float4*>(yb + j*4096 + e0);
    const float4* wr = reinterpret_cast<const float4*>(&WT[j*52]);
    #pragma unroll
    for (int g=0; g<12; g++){
      const float4 w = wr[g];     // broadcast b128
      acc[g*4+0].x += w.x*v.x; acc[g*4+0].y += w.x*v.y; acc[g*4+0].z += w.x*v.z; acc[g*4+0].w += w.x*v.w;
      acc[g*4+1].x += w.y*v.x; acc[g*4+1].y += w.y*v.y; acc[g*4+1].z += w.y*v.z; acc[g*4+1].w += w.y*v.w;
      acc[g*4+2].x += w.z*v.x; acc[g*4+2].y += w.z*v.y; acc[g*4+2].z += w.z*v.z; acc[g*4+2].w += w.z*v.w;
      acc[g*4+3].x += w.w*v.x; acc[g*4+3].y += w.w*v.y; acc[g*4+3].z += w.w*v.z; acc[g*4+3].w += w.w*v.w;
    }
    const float w48 = WT[j*52+48];
    acc[48].x += w48*v.x; acc[48].y += w48*v.y; acc[48].z += w48*v.z; acc[48].w += w48*v.w;
  }

  const int c  = e0 >> 4;
  const int p1 = (e0 >> 2) & 3;
  float* ob = out + bt*200704 + c*784 + p1*28;   // p2 = 0..3 contiguous
  #pragma unroll
  for (int i=0;i<49;i++){
    const float ci = cl[i];
    float4 o;
    o.x = acc[i].x + ci; o.y = acc[i].y + ci; o.z = acc[i].z + ci; o.w = acc[i].w + ci;
    *reinterpret_cast<float4*>(ob + (i/7)*112 + (i%7)*4) = o;
  }
}

extern "C" void kernel_launch(void* const* d_in, const int* in_sizes, int n_in,
                              void* d_out, int out_size, void* d_ws, size_t ws_size,
                              hipStream_t stream) {
  const float* x = (const float*)d_in[0];
  float* out = (float*)d_out;
  float* ws  = (float*)d_ws;
  float* y1   = ws;                     // 25,690,112 floats (102.8 MB)
  float* wsA  = y1 + 25690112;          // 512*2500 = 1,280,000 floats
  float* wsWT = wsA + 512*2500;         // 128*2548 = 326,144 floats (W^T + I, padded 52)
  float* wsC  = wsWT + 128*2548;        // 128*49   -> total ~109.2 MB
  // overlay (dead before k_s1 writes wsA): temporal partials + per-seq W
  float* wsG  = wsA;                    // 784*16*44 = 551,936 floats
  float* wsWt = wsA + 551936;           // 784*72   =  56,448 floats (fits in wsA)
  hipLaunchKernelGGL(k_t1, dim3(1792), dim3(256), 0, stream, x, wsG);
  hipLaunchKernelGGL(k_t2, dim3(784),  dim3(64),  0, stream, wsG, wsWt);
  hipLaunchKernelGGL(k_t3, dim3(1792), dim3(256), 0, stream, x, wsWt, y1);
  hipLaunchKernelGGL(k_s1, dim3(512),  dim3(256), 0, stream, y1, wsA);
  hipLaunchKernelGGL(k_s2, dim3(128),  dim3(256), 0, stream, wsA, wsWT, wsC);
  hipLaunchKernelGGL(k_s3, dim3(512),  dim3(256), 0, stream, y1, wsWT, wsC, out);
}

// Round 4
// 234.898 us; speedup vs baseline: 1.6599x; 1.0010x over previous
//
#include <hip/hip_runtime.h>

// x: (128, 256, 28, 28) fp32.  b=16, t=8, c=256, h=w=28, p=4, ph=pw=7, e=4096.
// y1 (ws): [bt][pp][e'], e' = c*16 + p1*4 + p2 (LN/attn are e-permutation invariant).

#define IDX36(a,b) ((((a)*8)+(b))-((((a)*((a)+1)))/2))

typedef __attribute__((ext_vector_type(8)))  short bf16x8;   // 8 bf16 (4 VGPRs)
typedef __attribute__((ext_vector_type(16))) float f32x16;   // 32x32 MFMA acc

__device__ __forceinline__ float wsum64(float v){
  #pragma unroll
  for (int off=32; off; off>>=1) v += __shfl_xor(v, off);
  return v;
}
__device__ __forceinline__ float wsum32(float v){
  #pragma unroll
  for (int off=16; off; off>>=1) v += __shfl_xor(v, off);
  return v;
}
__device__ __forceinline__ unsigned int rne_bf16(float f){
  unsigned int b = __float_as_uint(f);
  return (b + 0x7FFFu + ((b>>16)&1u)) >> 16;
}

// ---------------- temporal stage 1: partial Grams per c-slice ----------------
__global__ __launch_bounds__(256) void k_t1(const float* __restrict__ x, float* __restrict__ wsG){
  const int bx = blockIdx.x;
  const int b = bx / 112;
  const int ph = (bx % 112) / 16;
  const int slice = bx & 15;
  const int c0 = slice * 16;
  const int tid = threadIdx.x;

  __shared__ float lds[8*16*116];   // [t][c][116-padded stripe of 112 floats]
  const float4* x4 = reinterpret_cast<const float4*>(x);

  #pragma unroll
  for (int t=0;t<8;t++){
    const int base = ((b*8+t)*256 + c0)*196 + ph*28;
    {
      const int f = tid, c = f/28, m = f%28;
      *reinterpret_cast<float4*>(&lds[(t*16+c)*116 + m*4]) = x4[base + c*196 + m];
    }
    if (tid < 192){
      const int f = 256+tid, c = f/28, m = f%28;
      *reinterpret_cast<float4*>(&lds[(t*16+c)*116 + m*4]) = x4[base + c*196 + m];
    }
  }
  __syncthreads();

  const int pw   = tid >> 5;        // 0..6 valid; group 7 is idle-compute
  const int slot = tid & 31;
  const int c    = slot >> 1;
  const int p1b  = (slot & 1) * 2;

  float v[8][8];
  #pragma unroll
  for (int t=0;t<8;t++){
    const float* p = &lds[(t*16+c)*116 + p1b*28 + pw*4];
    const float4 a  = *reinterpret_cast<const float4*>(p);
    const float4 b2 = *reinterpret_cast<const float4*>(p + 28);
    v[t][0]=a.x;  v[t][1]=a.y;  v[t][2]=a.z;  v[t][3]=a.w;
    v[t][4]=b2.x; v[t][5]=b2.y; v[t][6]=b2.z; v[t][7]=b2.w;
  }

  float Au[36], sm[8];
  #pragma unroll
  for (int a2=0;a2<8;a2++){
    float s0 = 0.f;
    #pragma unroll
    for (int e=0;e<8;e++) s0 += v[a2][e];
    sm[a2] = s0;
    #pragma unroll
    for (int b2=a2;b2<8;b2++){
      float s = 0.f;
      #pragma unroll
      for (int e=0;e<8;e++) s += v[a2][e]*v[b2][e];
      Au[IDX36(a2,b2)] = s;
    }
  }
  #pragma unroll
  for (int i=0;i<36;i++) Au[i] = wsum32(Au[i]);
  #pragma unroll
  for (int t=0;t<8;t++) sm[t] = wsum32(sm[t]);

  if (slot == 0 && pw < 7){
    const int base = ((b*49 + ph*7 + pw)*16 + slice)*44;
    #pragma unroll
    for (int i=0;i<36;i++) wsG[base+i] = Au[i];
    #pragma unroll
    for (int t=0;t<8;t++)  wsG[base+36+t] = sm[t];
  }
}

// ---------------- temporal stage 2: reduce slices, softmax -> W, cc ----------------
__global__ __launch_bounds__(64) void k_t2(const float* __restrict__ wsG, float* __restrict__ wsWt){
  const int seq = blockIdx.x;
  const int lane = threadIdx.x;
  __shared__ float red[44];
  if (lane < 44){
    float a = 0.f;
    #pragma unroll
    for (int s=0;s<16;s++) a += wsG[(seq*16+s)*44 + lane];
    red[lane] = a;
  }
  __syncthreads();
  if (lane < 8){
    const int i = lane;
    float Ar[36], mean[8], rstd[8];
    #pragma unroll
    for (int k=0;k<36;k++) Ar[k] = red[k];
    #pragma unroll
    for (int t=0;t<8;t++){
      const float sv = red[36+t];
      mean[t] = sv * (1.f/4096.f);
      const float var = Ar[IDX36(t,t)] * (1.f/4096.f) - mean[t]*mean[t];
      rstd[t] = rsqrtf(var + 1e-5f);
    }
    #define GV(a,b) ((((a)<8)&&((b)<8)) ? (rstd[(a)]*rstd[(b)]*(Ar[((a)<=(b))?IDX36((a),(b)):IDX36((b),(a))] - 4096.f*mean[(a)]*mean[(b)])) : 0.f)
    float l[8]; float mx = -1e30f;
    #pragma unroll
    for (int j=0;j<8;j++){
      const float sij = GV(i+1,j+1) - GV(i+1,j) - GV(i,j+1) + GV(i,j);
      l[j] = sij * (1.f/64.f);
      mx = fmaxf(mx, l[j]);
    }
    float ss = 0.f;
    #pragma unroll
    for (int j=0;j<8;j++){ l[j] = __expf(l[j]-mx); ss += l[j]; }
    const float inv = 1.f/ss;
    float cc = 0.f;
    #pragma unroll
    for (int k2=0;k2<8;k2++){
      const float q = (((k2>=1)? l[k2-1] : 0.f) - l[k2]) * inv;
      const float wv2 = q * rstd[k2];
      wsWt[seq*72 + i*8 + k2] = wv2;
      cc -= wv2 * mean[k2];
    }
    wsWt[seq*72 + 64 + i] = cc;
    #undef GV
  }
}

// ---------------- temporal stage 3: recombine + write y1 ----------------
__global__ __launch_bounds__(256) void k_t3(const float* __restrict__ x, const float* __restrict__ wsWt,
                                            float* __restrict__ y1){
  const int bx = blockIdx.x;
  const int b = bx / 112;
  const int ph = (bx % 112) / 16;
  const int slice = bx & 15;
  const int c0 = slice * 16;
  const int tid = threadIdx.x;

  __shared__ float Wl[7][72];
  for (int idx=tid; idx<504; idx+=256)
    Wl[idx/72][idx%72] = wsWt[(b*49 + ph*7 + idx/72)*72 + idx%72];
  __syncthreads();

  const float4* x4 = reinterpret_cast<const float4*>(x);
  float4* y4 = reinterpret_cast<float4*>(y1);

  #pragma unroll
  for (int fi=0; fi<2; fi++){
    const int f = fi*256 + tid;
    if (f < 448){
      const int c = f/28, m = f%28, pw = m%7, p1 = m/7;
      float4 v[8];
      #pragma unroll
      for (int t=0;t<8;t++) v[t] = x4[((b*8+t)*256 + c0+c)*196 + ph*28 + m];
      const float* W = Wl[pw];
      const int pp = ph*7 + pw;
      #pragma unroll
      for (int i=0;i<8;i++){
        const float ci = W[64+i];
        float4 o;
        o.x = v[i].x + ci; o.y = v[i].y + ci; o.z = v[i].z + ci; o.w = v[i].w + ci;
        #pragma unroll
        for (int j=0;j<8;j++){
          const float w = W[i*8+j];
          o.x += w*v[j].x; o.y += w*v[j].y; o.z += w*v[j].z; o.w += w*v[j].w;
        }
        y4[((b*8+i)*49 + pp)*1024 + (c0+c)*4 + p1] = o;
      }
    }
  }
}

// ---------------- spatial stage: Gram partials via split-bf16 MFMA ----------------
// grid = 128 bt * 4 K-slices (K=1024). G = Hi*Hi^T + Hi*Lo^T + Lo*Hi^T (Lo*Lo dropped, ~2^-16 rel).
// For a Gram, the 32x32x16 A-frag and B-frag of the same row-range are the SAME LDS read:
// lane l -> row (l&31), k (l>>5)*8. 4 ds_read_b128 -> 12 MFMAs per k-step per wave.
__global__ __launch_bounds__(256,2) void k_s1(const float* __restrict__ y1, float* __restrict__ wsA){
  const int bt = blockIdx.x >> 2;
  const int slice = blockIdx.x & 3;
  const int tid = threadIdx.x;
  const int wave = tid >> 6, lane = tid & 63;

  __shared__ unsigned short Ah[64*136];   // stride 136 bf16 = 68 words -> conflict-free b128
  __shared__ unsigned short Al[64*136];
  __shared__ float red[64*52];

  for (int i=tid; i<64*52; i+=256) red[i] = 0.f;

  f32x16 acc00, acc01, acc10, acc11;
  #pragma unroll
  for (int i=0;i<16;i++){ acc00[i]=0.f; acc01[i]=0.f; acc10[i]=0.f; acc11[i]=0.f; }

  const float* yb = y1 + bt*49*4096 + slice*1024;
  const int j = tid >> 2, q = tid & 3;   // row j (0..63), k-quarter q (32 floats)
  const int r0 = lane & 31;
  const int koff = (lane >> 5) * 8;

  for (int ch=0; ch<8; ++ch){
    __syncthreads();                     // previous compute done before overwrite
    unsigned int hp[16], lp[16];
    if (j < 49){
      const float* p = yb + j*4096 + ch*128 + q*32;
      #pragma unroll
      for (int i4=0;i4<8;i4++){
        const float4 v = *reinterpret_cast<const float4*>(p + i4*4);
        float vv[4] = {v.x, v.y, v.z, v.w};
        unsigned int hh[4], ll[4];
        #pragma unroll
        for (int e=0;e<4;e++){
          const float f = vv[e];
          const unsigned int h = rne_bf16(f);
          const float hf = __uint_as_float(h << 16);
          hh[e] = h;
          ll[e] = rne_bf16(f - hf);
        }
        hp[i4*2+0] = hh[0] | (hh[1]<<16);  hp[i4*2+1] = hh[2] | (hh[3]<<16);
        lp[i4*2+0] = ll[0] | (ll[1]<<16);  lp[i4*2+1] = ll[2] | (ll[3]<<16);
      }
    } else {
      const unsigned int hv = (j == 49) ? 0x3F803F80u : 0u;  // ones row (token 49)
      #pragma unroll
      for (int i=0;i<16;i++){ hp[i] = hv; lp[i] = 0u; }
    }
    const int base = j*136 + q*32;
    #pragma unroll
    for (int g=0; g<4; ++g){
      *reinterpret_cast<uint4*>(&Ah[base + g*8]) = make_uint4(hp[g*4],hp[g*4+1],hp[g*4+2],hp[g*4+3]);
      *reinterpret_cast<uint4*>(&Al[base + g*8]) = make_uint4(lp[g*4],lp[g*4+1],lp[g*4+2],lp[g*4+3]);
    }
    __syncthreads();

    #pragma unroll
    for (int kk=0; kk<2; ++kk){
      const int kw = (wave + kk*4) * 16;   // split-K across waves: k-step of 16 bf16
      const bf16x8 f0h = *reinterpret_cast<const bf16x8*>(&Ah[ r0     *136 + kw + koff]);
      const bf16x8 f0l = *reinterpret_cast<const bf16x8*>(&Al[ r0     *136 + kw + koff]);
      const bf16x8 f1h = *reinterpret_cast<const bf16x8*>(&Ah[(32+r0)*136 + kw + koff]);
      const bf16x8 f1l = *reinterpret_cast<const bf16x8*>(&Al[(32+r0)*136 + kw + koff]);
      acc00 = __builtin_amdgcn_mfma_f32_32x32x16_bf16(f0h, f0h, acc00, 0,0,0);
      acc00 = __builtin_amdgcn_mfma_f32_32x32x16_bf16(f0h, f0l, acc00, 0,0,0);
      acc00 = __builtin_amdgcn_mfma_f32_32x32x16_bf16(f0l, f0h, acc00, 0,0,0);
      acc01 = __builtin_amdgcn_mfma_f32_32x32x16_bf16(f0h, f1h, acc01, 0,0,0);
      acc01 = __builtin_amdgcn_mfma_f32_32x32x16_bf16(f0h, f1l, acc01, 0,0,0);
      acc01 = __builtin_amdgcn_mfma_f32_32x32x16_bf16(f0l, f1h, acc01, 0,0,0);
      acc10 = __builtin_amdgcn_mfma_f32_32x32x16_bf16(f1h, f0h, acc10, 0,0,0);
      acc10 = __builtin_amdgcn_mfma_f32_32x32x16_bf16(f1h, f0l, acc10, 0,0,0);
      acc10 = __builtin_amdgcn_mfma_f32_32x32x16_bf16(f1l, f0h, acc10, 0,0,0);
      acc11 = __builtin_amdgcn_mfma_f32_32x32x16_bf16(f1h, f1h, acc11, 0,0,0);
      acc11 = __builtin_amdgcn_mfma_f32_32x32x16_bf16(f1h, f1l, acc11, 0,0,0);
      acc11 = __builtin_amdgcn_mfma_f32_32x32x16_bf16(f1l, f1h, acc11, 0,0,0);
    }
  }
  __syncthreads();

  // cross-wave reduce: C layout col=lane&31, row=(reg&3)+8*(reg>>2)+4*(lane>>5)
  const int ccol = lane & 31;
  const int rbase = 4*(lane>>5);
  #pragma unroll
  for (int q2=0;q2<16;q2++){
    const int rr = (q2&3) + 8*(q2>>2) + rbase;
    atomicAdd(&red[ rr    *52 + ccol     ], acc00[q2]);
    atomicAdd(&red[ rr    *52 + 32 + ccol], acc01[q2]);
    atomicAdd(&red[(rr+32)*52 + ccol     ], acc10[q2]);
    atomicAdd(&red[(rr+32)*52 + 32 + ccol], acc11[q2]);
  }
  __syncthreads();
  float* wp = wsA + blockIdx.x * 2500;
  for (int idx=tid; idx<2500; idx+=256) wp[idx] = red[(idx/50)*52 + idx%50];
}

// ---------------- spatial stage: softmax -> WT (+I folded, padded 52), c ----------------
__global__ __launch_bounds__(256) void k_s2(const float* __restrict__ wsA, float* __restrict__ wsWT, float* __restrict__ wsC){
  const int bt = blockIdx.x;
  const int tid = threadIdx.x;
  __shared__ float A[2500];
  __shared__ float m[49], r[49];
  for (int idx=tid; idx<2548; idx+=256) wsWT[bt*2548+idx] = 0.f;
  for (int idx=tid; idx<2500; idx+=256){
    float v = 0.f;
    #pragma unroll
    for (int sl=0; sl<4; sl++) v += wsA[(bt*4+sl)*2500 + idx];
    A[idx] = v;
  }
  __syncthreads();
  if (tid < 49){
    const float mm = A[49*50+tid] * (1.f/4096.f);        // row 49 = ones row -> sums
    const float var = A[tid*50+tid] * (1.f/4096.f) - mm*mm;
    m[tid]=mm; r[tid]=rsqrtf(var+1e-5f);
  }
  __syncthreads();
  const int wv = tid>>6, lane = tid&63;
  for (int i=wv; i<49; i+=4){
    const float ri = r[i], mi = m[i];
    float rv=0.f, mv=0.f, L=-1e30f;
    if (lane < 49){
      rv = r[lane]; mv = m[lane];
      L = ri*rv*(A[i*50+lane] - 4096.f*mi*mv) * (1.f/64.f);
    }
    float mx = L;
    #pragma unroll
    for (int off=32; off; off>>=1) mx = fmaxf(mx, __shfl_xor(mx, off));
    const float p = (lane<49) ? __expf(L-mx) : 0.f;
    const float ss = wsum64(p);
    const float Wv = (p/ss)*rv;
    if (lane < 49) wsWT[bt*2548 + lane*52 + i] = Wv + ((lane==i) ? 1.f : 0.f);
    const float cp = wsum64(-Wv*mv);
    if (lane == 0) wsC[bt*49+i] = cp;
  }
}

// ---------------- spatial stage: recombine + scatter back to x layout ----------------
__global__ __launch_bounds__(256,2) void k_s3(const float* __restrict__ y1, const float* __restrict__ wsWT,
                                              const float* __restrict__ wsC, float* __restrict__ out){
  const int bt = blockIdx.x >> 2;
  const int chunk = blockIdx.x & 3;
  const int tid = threadIdx.x;
  __shared__ float WT[49*52];
  __shared__ float cl[49];
  for (int idx=tid; idx<2548; idx+=256) WT[idx] = wsWT[bt*2548+idx];
  if (tid < 49) cl[tid] = wsC[bt*49+tid];
  __syncthreads();

  const int e0 = chunk*1024 + tid*4;
  float4 acc[49];
  #pragma unroll
  for (int i=0;i<49;i++){ acc[i].x=0.f; acc[i].y=0.f; acc[i].z=0.f; acc[i].w=0.f; }
  const float* yb = y1 + bt*49*4096;

  for (int j=0;j<49;++j){
    const float4 v = *reinterpret_cast<const float4*>(yb + j*4096 + e0);
    const float4* wr = reinterpret_cast<const float4*>(&WT[j*52]);
    #pragma unroll
    for (int g=0; g<12; g++){
      const float4 w = wr[g];     // broadcast b128
      acc[g*4+0].x += w.x*v.x; acc[g*4+0].y += w.x*v.y; acc[g*4+0].z += w.x*v.z; acc[g*4+0].w += w.x*v.w;
      acc[g*4+1].x += w.y*v.x; acc[g*4+1].y += w.y*v.y; acc[g*4+1].z += w.y*v.z; acc[g*4+1].w += w.y*v.w;
      acc[g*4+2].x += w.z*v.x; acc[g*4+2].y += w.z*v.y; acc[g*4+2].z += w.z*v.z; acc[g*4+2].w += w.z*v.w;
      acc[g*4+3].x += w.w*v.x; acc[g*4+3].y += w.w*v.y; acc[g*4+3].z += w.w*v.z; acc[g*4+3].w += w.w*v.w;
    }
    const float w48 = WT[j*52+48];
    acc[48].x += w48*v.x; acc[48].y += w48*v.y; acc[48].z += w48*v.z; acc[48].w += w48*v.w;
  }

  const int c  = e0 >> 4;
  const int p1 = (e0 >> 2) & 3;
  float* ob = out + bt*200704 + c*784 + p1*28;   // p2 = 0..3 contiguous
  #pragma unroll
  for (int i=0;i<49;i++){
    const float ci = cl[i];
    float4 o;
    o.x = acc[i].x + ci; o.y = acc[i].y + ci; o.z = acc[i].z + ci; o.w = acc[i].w + ci;
    *reinterpret_cast<float4*>(ob + (i/7)*112 + (i%7)*4) = o;
  }
}

extern "C" void kernel_launch(void* const* d_in, const int* in_sizes, int n_in,
                              void* d_out, int out_size, void* d_ws, size_t ws_size,
                              hipStream_t stream) {
  const float* x = (const float*)d_in[0];
  float* out = (float*)d_out;
  float* ws  = (float*)d_ws;
  float* y1   = ws;                     // 25,690,112 floats (102.8 MB)
  float* wsA  = y1 + 25690112;          // 512*2500 = 1,280,000 floats
  float* wsWT = wsA + 512*2500;         // 128*2548 = 326,144 floats (W^T + I, padded 52)
  float* wsC  = wsWT + 128*2548;        // 128*49   -> total ~109.2 MB
  // overlay (dead before k_s1 writes wsA): temporal partials + per-seq W
  float* wsG  = wsA;                    // 784*16*44 = 551,936 floats
  float* wsWt = wsA + 551936;           // 784*72   =  56,448 floats (fits in wsA)
  hipLaunchKernelGGL(k_t1, dim3(1792), dim3(256), 0, stream, x, wsG);
  hipLaunchKernelGGL(k_t2, dim3(784),  dim3(64),  0, stream, wsG, wsWt);
  hipLaunchKernelGGL(k_t3, dim3(1792), dim3(256), 0, stream, x, wsWt, y1);
  hipLaunchKernelGGL(k_s1, dim3(512),  dim3(256), 0, stream, y1, wsA);
  hipLaunchKernelGGL(k_s2, dim3(128),  dim3(256), 0, stream, wsA, wsWT, wsC);
  hipLaunchKernelGGL(k_s3, dim3(512),  dim3(256), 0, stream, y1, wsWT, wsC, out);
}

// Round 5
// 218.398 us; speedup vs baseline: 1.7853x; 1.0756x over previous
//
#include <hip/hip_runtime.h>

// x: (128, 256, 28, 28) fp32.  b=16, t=8, c=256, h=w=28, p=4, ph=pw=7, e=4096.
// y1 (ws): [bt][pp][e'], e' = c*16 + p1*4 + p2 (LN/attn are e-permutation invariant).

#define IDX36(a,b) ((((a)*8)+(b))-((((a)*((a)+1)))/2))

typedef __attribute__((ext_vector_type(8)))  short bf16x8;   // 8 bf16 (4 VGPRs)
typedef __attribute__((ext_vector_type(16))) float f32x16;   // 32x32 MFMA acc

__device__ __forceinline__ float wsum64(float v){
  #pragma unroll
  for (int off=32; off; off>>=1) v += __shfl_xor(v, off);
  return v;
}
__device__ __forceinline__ float wsum32(float v){
  #pragma unroll
  for (int off=16; off; off>>=1) v += __shfl_xor(v, off);
  return v;
}
__device__ __forceinline__ unsigned int rne_bf16(float f){
  unsigned int b = __float_as_uint(f);
  return (b + 0x7FFFu + ((b>>16)&1u)) >> 16;
}

// ---------------- temporal stage 1: partial Grams per c-slice ----------------
__global__ __launch_bounds__(256) void k_t1(const float* __restrict__ x, float* __restrict__ wsG){
  const int bx = blockIdx.x;
  const int b = bx / 112;
  const int ph = (bx % 112) / 16;
  const int slice = bx & 15;
  const int c0 = slice * 16;
  const int tid = threadIdx.x;

  __shared__ float lds[8*16*116];   // [t][c][116-padded stripe of 112 floats]
  const float4* x4 = reinterpret_cast<const float4*>(x);

  #pragma unroll
  for (int t=0;t<8;t++){
    const int base = ((b*8+t)*256 + c0)*196 + ph*28;
    {
      const int f = tid, c = f/28, m = f%28;
      *reinterpret_cast<float4*>(&lds[(t*16+c)*116 + m*4]) = x4[base + c*196 + m];
    }
    if (tid < 192){
      const int f = 256+tid, c = f/28, m = f%28;
      *reinterpret_cast<float4*>(&lds[(t*16+c)*116 + m*4]) = x4[base + c*196 + m];
    }
  }
  __syncthreads();

  const int pw   = tid >> 5;        // 0..6 valid; group 7 is idle-compute
  const int slot = tid & 31;
  const int c    = slot >> 1;
  const int p1b  = (slot & 1) * 2;

  float v[8][8];
  #pragma unroll
  for (int t=0;t<8;t++){
    const float* p = &lds[(t*16+c)*116 + p1b*28 + pw*4];
    const float4 a  = *reinterpret_cast<const float4*>(p);
    const float4 b2 = *reinterpret_cast<const float4*>(p + 28);
    v[t][0]=a.x;  v[t][1]=a.y;  v[t][2]=a.z;  v[t][3]=a.w;
    v[t][4]=b2.x; v[t][5]=b2.y; v[t][6]=b2.z; v[t][7]=b2.w;
  }

  float Au[36], sm[8];
  #pragma unroll
  for (int a2=0;a2<8;a2++){
    float s0 = 0.f;
    #pragma unroll
    for (int e=0;e<8;e++) s0 += v[a2][e];
    sm[a2] = s0;
    #pragma unroll
    for (int b2=a2;b2<8;b2++){
      float s = 0.f;
      #pragma unroll
      for (int e=0;e<8;e++) s += v[a2][e]*v[b2][e];
      Au[IDX36(a2,b2)] = s;
    }
  }
  #pragma unroll
  for (int i=0;i<36;i++) Au[i] = wsum32(Au[i]);
  #pragma unroll
  for (int t=0;t<8;t++) sm[t] = wsum32(sm[t]);

  if (slot == 0 && pw < 7){
    const int base = ((b*49 + ph*7 + pw)*16 + slice)*44;
    #pragma unroll
    for (int i=0;i<36;i++) wsG[base+i] = Au[i];
    #pragma unroll
    for (int t=0;t<8;t++)  wsG[base+36+t] = sm[t];
  }
}

// ---------------- temporal stage 2: reduce slices, softmax -> W, cc ----------------
__global__ __launch_bounds__(64) void k_t2(const float* __restrict__ wsG, float* __restrict__ wsWt){
  const int seq = blockIdx.x;
  const int lane = threadIdx.x;
  __shared__ float red[44];
  if (lane < 44){
    float a = 0.f;
    #pragma unroll
    for (int s=0;s<16;s++) a += wsG[(seq*16+s)*44 + lane];
    red[lane] = a;
  }
  __syncthreads();
  if (lane < 8){
    const int i = lane;
    float Ar[36], mean[8], rstd[8];
    #pragma unroll
    for (int k=0;k<36;k++) Ar[k] = red[k];
    #pragma unroll
    for (int t=0;t<8;t++){
      const float sv = red[36+t];
      mean[t] = sv * (1.f/4096.f);
      const float var = Ar[IDX36(t,t)] * (1.f/4096.f) - mean[t]*mean[t];
      rstd[t] = rsqrtf(var + 1e-5f);
    }
    #define GV(a,b) ((((a)<8)&&((b)<8)) ? (rstd[(a)]*rstd[(b)]*(Ar[((a)<=(b))?IDX36((a),(b)):IDX36((b),(a))] - 4096.f*mean[(a)]*mean[(b)])) : 0.f)
    float l[8]; float mx = -1e30f;
    #pragma unroll
    for (int j=0;j<8;j++){
      const float sij = GV(i+1,j+1) - GV(i+1,j) - GV(i,j+1) + GV(i,j);
      l[j] = sij * (1.f/64.f);
      mx = fmaxf(mx, l[j]);
    }
    float ss = 0.f;
    #pragma unroll
    for (int j=0;j<8;j++){ l[j] = __expf(l[j]-mx); ss += l[j]; }
    const float inv = 1.f/ss;
    float cc = 0.f;
    #pragma unroll
    for (int k2=0;k2<8;k2++){
      const float q = (((k2>=1)? l[k2-1] : 0.f) - l[k2]) * inv;
      const float wv2 = q * rstd[k2];
      wsWt[seq*72 + i*8 + k2] = wv2;
      cc -= wv2 * mean[k2];
    }
    wsWt[seq*72 + 64 + i] = cc;
    #undef GV
  }
}

// ---------------- temporal stage 3: recombine + write y1 ----------------
__global__ __launch_bounds__(256) void k_t3(const float* __restrict__ x, const float* __restrict__ wsWt,
                                            float* __restrict__ y1){
  const int bx = blockIdx.x;
  const int b = bx / 112;
  const int ph = (bx % 112) / 16;
  const int slice = bx & 15;
  const int c0 = slice * 16;
  const int tid = threadIdx.x;

  __shared__ float Wl[7][72];
  for (int idx=tid; idx<504; idx+=256)
    Wl[idx/72][idx%72] = wsWt[(b*49 + ph*7 + idx/72)*72 + idx%72];
  __syncthreads();

  const float4* x4 = reinterpret_cast<const float4*>(x);
  float4* y4 = reinterpret_cast<float4*>(y1);

  #pragma unroll
  for (int fi=0; fi<2; fi++){
    const int f = fi*256 + tid;
    if (f < 448){
      const int c = f/28, m = f%28, pw = m%7, p1 = m/7;
      float4 v[8];
      #pragma unroll
      for (int t=0;t<8;t++) v[t] = x4[((b*8+t)*256 + c0+c)*196 + ph*28 + m];
      const float* W = Wl[pw];
      const int pp = ph*7 + pw;
      #pragma unroll
      for (int i=0;i<8;i++){
        const float ci = W[64+i];
        float4 o;
        o.x = v[i].x + ci; o.y = v[i].y + ci; o.z = v[i].z + ci; o.w = v[i].w + ci;
        #pragma unroll
        for (int j=0;j<8;j++){
          const float w = W[i*8+j];
          o.x += w*v[j].x; o.y += w*v[j].y; o.z += w*v[j].z; o.w += w*v[j].w;
        }
        y4[((b*8+i)*49 + pp)*1024 + (c0+c)*4 + p1] = o;
      }
    }
  }
}

// ---------------- spatial stage: Gram partials via split-bf16 MFMA ----------------
// grid = 128 bt * 4 K-slices (K=1024). G = Hi*Hi^T + Hi*Lo^T + Lo*Hi^T (Lo*Lo dropped).
// Coalesced loads (whole 512B rows per instr) + reg ping-pong prefetch; upper tiles
// only (G symmetric), mirror at writeout.
__global__ __launch_bounds__(256,2) void k_s1(const float* __restrict__ y1, float* __restrict__ wsA){
  const int bt = blockIdx.x >> 2;
  const int slice = blockIdx.x & 3;
  const int tid = threadIdx.x;
  const int wave = tid >> 6, lane = tid & 63;

  __shared__ unsigned short Ah[64*136];
  __shared__ unsigned short Al[64*136];
  __shared__ float red[64*52];

  for (int i=tid; i<64*52; i+=256) red[i] = 0.f;

  f32x16 acc00, acc01, acc11;
  #pragma unroll
  for (int i=0;i<16;i++){ acc00[i]=0.f; acc01[i]=0.f; acc11[i]=0.f; }

  const float4* yb4 = reinterpret_cast<const float4*>(y1 + bt*49*4096 + slice*1024);
  const int rgrp = tid >> 5;            // 0..7: row sub-group
  const int col4 = tid & 31;            // float4 column within 128-float chunk
  const int r0 = lane & 31;
  const int koff = (lane >> 5) * 8;

#define ISSUE_CH(pf, ch) { \
  _Pragma("unroll") \
  for (int i=0;i<7;i++) pf[i] = yb4[(i*8 + rgrp)*1024 + (ch)*32 + col4]; }

#define CW_CH(pf) { \
  _Pragma("unroll") \
  for (int i=0;i<8;i++){ \
    unsigned int h01,h23,l01,l23; \
    if (i==7){ h01=0u; h23=0u; l01=0u; l23=0u; } \
    else { \
      const float4 v = pf[i]; \
      const unsigned int u0=__float_as_uint(v.x), u1=__float_as_uint(v.y); \
      const unsigned int u2=__float_as_uint(v.z), u3=__float_as_uint(v.w); \
      const float l0 = v.x-__uint_as_float(u0&0xFFFF0000u); \
      const float l1 = v.y-__uint_as_float(u1&0xFFFF0000u); \
      const float l2 = v.z-__uint_as_float(u2&0xFFFF0000u); \
      const float l3 = v.w-__uint_as_float(u3&0xFFFF0000u); \
      h01 = (u0>>16)|(u1&0xFFFF0000u); h23 = (u2>>16)|(u3&0xFFFF0000u); \
      l01 = rne_bf16(l0)|(rne_bf16(l1)<<16); l23 = rne_bf16(l2)|(rne_bf16(l3)<<16); \
      if (i==6){ \
        const bool valid = (rgrp==0); const bool ones = (rgrp==1); \
        h01 = valid ? h01 : (ones ? 0x3F803F80u : 0u); \
        h23 = valid ? h23 : (ones ? 0x3F803F80u : 0u); \
        l01 = valid ? l01 : 0u; l23 = valid ? l23 : 0u; \
      } \
    } \
    const int wb = (i*8+rgrp)*136 + col4*4; \
    *reinterpret_cast<uint2*>(&Ah[wb]) = make_uint2(h01,h23); \
    *reinterpret_cast<uint2*>(&Al[wb]) = make_uint2(l01,l23); \
  } }

#define MFMA_CH() { \
  _Pragma("unroll") \
  for (int kk=0;kk<2;kk++){ \
    const int kw = (wave + kk*4)*16; \
    const bf16x8 f0h = *reinterpret_cast<const bf16x8*>(&Ah[ r0     *136 + kw + koff]); \
    const bf16x8 f0l = *reinterpret_cast<const bf16x8*>(&Al[ r0     *136 + kw + koff]); \
    const bf16x8 f1h = *reinterpret_cast<const bf16x8*>(&Ah[(32+r0)*136 + kw + koff]); \
    const bf16x8 f1l = *reinterpret_cast<const bf16x8*>(&Al[(32+r0)*136 + kw + koff]); \
    acc00 = __builtin_amdgcn_mfma_f32_32x32x16_bf16(f0h, f0h, acc00, 0,0,0); \
    acc00 = __builtin_amdgcn_mfma_f32_32x32x16_bf16(f0h, f0l, acc00, 0,0,0); \
    acc00 = __builtin_amdgcn_mfma_f32_32x32x16_bf16(f0l, f0h, acc00, 0,0,0); \
    acc01 = __builtin_amdgcn_mfma_f32_32x32x16_bf16(f0h, f1h, acc01, 0,0,0); \
    acc01 = __builtin_amdgcn_mfma_f32_32x32x16_bf16(f0h, f1l, acc01, 0,0,0); \
    acc01 = __builtin_amdgcn_mfma_f32_32x32x16_bf16(f0l, f1h, acc01, 0,0,0); \
    acc11 = __builtin_amdgcn_mfma_f32_32x32x16_bf16(f1h, f1h, acc11, 0,0,0); \
    acc11 = __builtin_amdgcn_mfma_f32_32x32x16_bf16(f1h, f1l, acc11, 0,0,0); \
    acc11 = __builtin_amdgcn_mfma_f32_32x32x16_bf16(f1l, f1h, acc11, 0,0,0); \
  } }

  float4 pfA[7], pfB[7];
  ISSUE_CH(pfA, 0);
  #pragma unroll
  for (int ch=0; ch<8; ch+=2){
    if (ch+1<8) ISSUE_CH(pfB, ch+1);
    __syncthreads();                 // prev MFMA done reading LDS
    CW_CH(pfA);                      // waits only pfA's loads (older)
    __syncthreads();
    MFMA_CH();
    if (ch+2<8) ISSUE_CH(pfA, ch+2);
    __syncthreads();
    CW_CH(pfB);
    __syncthreads();
    MFMA_CH();
  }
  __syncthreads();

  // cross-wave reduce (upper tiles): C layout col=lane&31, row=(reg&3)+8*(reg>>2)+4*(lane>>5)
  const int ccol = lane & 31;
  const int rbase = 4*(lane>>5);
  #pragma unroll
  for (int q2=0;q2<16;q2++){
    const int rr = (q2&3) + 8*(q2>>2) + rbase;
    atomicAdd(&red[ rr    *52 + ccol     ], acc00[q2]);
    atomicAdd(&red[ rr    *52 + 32 + ccol], acc01[q2]);
    atomicAdd(&red[(rr+32)*52 + 32 + ccol], acc11[q2]);
  }
  __syncthreads();
  float* wp = wsA + blockIdx.x * 2500;
  for (int idx=tid; idx<2500; idx+=256){
    const int i2 = idx/50, j2 = idx%50;
    wp[idx] = (i2>=32 && j2<32) ? red[j2*52+i2] : red[i2*52+j2];
  }
#undef ISSUE_CH
#undef CW_CH
#undef MFMA_CH
}

// ---------------- spatial stage: softmax -> WT (+I folded, padded 52), c ----------------
__global__ __launch_bounds__(256) void k_s2(const float* __restrict__ wsA, float* __restrict__ wsWT, float* __restrict__ wsC){
  const int bt = blockIdx.x;
  const int tid = threadIdx.x;
  __shared__ float A[2500];
  __shared__ float m[49], r[49];
  for (int idx=tid; idx<2548; idx+=256) wsWT[bt*2548+idx] = 0.f;
  for (int idx=tid; idx<2500; idx+=256){
    float v = 0.f;
    #pragma unroll
    for (int sl=0; sl<4; sl++) v += wsA[(bt*4+sl)*2500 + idx];
    A[idx] = v;
  }
  __syncthreads();
  if (tid < 49){
    const float mm = A[49*50+tid] * (1.f/4096.f);        // row 49 = ones row -> sums
    const float var = A[tid*50+tid] * (1.f/4096.f) - mm*mm;
    m[tid]=mm; r[tid]=rsqrtf(var+1e-5f);
  }
  __syncthreads();
  const int wv = tid>>6, lane = tid&63;
  for (int i=wv; i<49; i+=4){
    const float ri = r[i], mi = m[i];
    float rv=0.f, mv=0.f, L=-1e30f;
    if (lane < 49){
      rv = r[lane]; mv = m[lane];
      L = ri*rv*(A[i*50+lane] - 4096.f*mi*mv) * (1.f/64.f);
    }
    float mx = L;
    #pragma unroll
    for (int off=32; off; off>>=1) mx = fmaxf(mx, __shfl_xor(mx, off));
    const float p = (lane<49) ? __expf(L-mx) : 0.f;
    const float ss = wsum64(p);
    const float Wv = (p/ss)*rv;
    if (lane < 49) wsWT[bt*2548 + lane*52 + i] = Wv + ((lane==i) ? 1.f : 0.f);
    const float cp = wsum64(-Wv*mv);
    if (lane == 0) wsC[bt*49+i] = cp;
  }
}

// ---------------- spatial stage: recombine + scatter back to x layout ----------------
__global__ __launch_bounds__(256,2) void k_s3(const float* __restrict__ y1, const float* __restrict__ wsWT,
                                              const float* __restrict__ wsC, float* __restrict__ out){
  const int bt = blockIdx.x >> 2;
  const int chunk = blockIdx.x & 3;
  const int tid = threadIdx.x;
  __shared__ float WT[49*52];
  __shared__ float cl[49];
  for (int idx=tid; idx<2548; idx+=256) WT[idx] = wsWT[bt*2548+idx];
  if (tid < 49) cl[tid] = wsC[bt*49+tid];
  __syncthreads();

  const int e0 = chunk*1024 + tid*4;
  float4 acc[49];
  #pragma unroll
  for (int i=0;i<49;i++){ acc[i].x=0.f; acc[i].y=0.f; acc[i].z=0.f; acc[i].w=0.f; }
  const float* yb = y1 + bt*49*4096;

  for (int j=0;j<49;++j){
    const float4 v = *reinterpret_cast<const float4*>(yb + j*4096 + e0);
    const float4* wr = reinterpret_cast<const float4*>(&WT[j*52]);
    #pragma unroll
    for (int g=0; g<12; g++){
      const float4 w = wr[g];     // broadcast b128
      acc[g*4+0].x += w.x*v.x; acc[g*4+0].y += w.x*v.y; acc[g*4+0].z += w.x*v.z; acc[g*4+0].w += w.x*v.w;
      acc[g*4+1].x += w.y*v.x; acc[g*4+1].y += w.y*v.y; acc[g*4+1].z += w.y*v.z; acc[g*4+1].w += w.y*v.w;
      acc[g*4+2].x += w.z*v.x; acc[g*4+2].y += w.z*v.y; acc[g*4+2].z += w.z*v.z; acc[g*4+2].w += w.z*v.w;
      acc[g*4+3].x += w.w*v.x; acc[g*4+3].y += w.w*v.y; acc[g*4+3].z += w.w*v.z; acc[g*4+3].w += w.w*v.w;
    }
    const float w48 = WT[j*52+48];
    acc[48].x += w48*v.x; acc[48].y += w48*v.y; acc[48].z += w48*v.z; acc[48].w += w48*v.w;
  }

  const int c  = e0 >> 4;
  const int p1 = (e0 >> 2) & 3;
  float* ob = out + bt*200704 + c*784 + p1*28;   // p2 = 0..3 contiguous
  #pragma unroll
  for (int i=0;i<49;i++){
    const float ci = cl[i];
    float4 o;
    o.x = acc[i].x + ci; o.y = acc[i].y + ci; o.z = acc[i].z + ci; o.w = acc[i].w + ci;
    *reinterpret_cast<float4*>(ob + (i/7)*112 + (i%7)*4) = o;
  }
}

extern "C" void kernel_launch(void* const* d_in, const int* in_sizes, int n_in,
                              void* d_out, int out_size, void* d_ws, size_t ws_size,
                              hipStream_t stream) {
  const float* x = (const float*)d_in[0];
  float* out = (float*)d_out;
  float* ws  = (float*)d_ws;
  float* y1   = ws;                     // 25,690,112 floats (102.8 MB)
  float* wsA  = y1 + 25690112;          // 512*2500 = 1,280,000 floats
  float* wsWT = wsA + 512*2500;         // 128*2548 = 326,144 floats (W^T + I, padded 52)
  float* wsC  = wsWT + 128*2548;        // 128*49   -> total ~109.2 MB
  // overlay (dead before k_s1 writes wsA): temporal partials + per-seq W
  float* wsG  = wsA;                    // 784*16*44 = 551,936 floats
  float* wsWt = wsA + 551936;           // 784*72   =  56,448 floats (fits in wsA)
  hipLaunchKernelGGL(k_t1, dim3(1792), dim3(256), 0, stream, x, wsG);
  hipLaunchKernelGGL(k_t2, dim3(784),  dim3(64),  0, stream, wsG, wsWt);
  hipLaunchKernelGGL(k_t3, dim3(1792), dim3(256), 0, stream, x, wsWt, y1);
  hipLaunchKernelGGL(k_s1, dim3(512),  dim3(256), 0, stream, y1, wsA);
  hipLaunchKernelGGL(k_s2, dim3(128),  dim3(256), 0, stream, wsA, wsWT, wsC);
  hipLaunchKernelGGL(k_s3, dim3(512),  dim3(256), 0, stream, y1, wsWT, wsC, out);
}

// Round 6
// 211.018 us; speedup vs baseline: 1.8477x; 1.0350x over previous
//
#include <hip/hip_runtime.h>

// x: (128, 256, 28, 28) fp32.  b=16, t=8, c=256, h=w=28, p=4, ph=pw=7, e=4096.
// y1 (ws): [bt][pp][e'], e' = c*16 + p1*4 + p2 (LN/attn are e-permutation invariant).

#define IDX36(a,b) ((((a)*8)+(b))-((((a)*((a)+1)))/2))

typedef __attribute__((ext_vector_type(8)))  short bf16x8;   // 8 bf16 (4 VGPRs)
typedef __attribute__((ext_vector_type(16))) float f32x16;   // 32x32 MFMA acc

__device__ __forceinline__ float wsum64(float v){
  #pragma unroll
  for (int off=32; off; off>>=1) v += __shfl_xor(v, off);
  return v;
}
__device__ __forceinline__ float wsum32(float v){
  #pragma unroll
  for (int off=16; off; off>>=1) v += __shfl_xor(v, off);
  return v;
}
__device__ __forceinline__ unsigned int rne_bf16(float f){
  unsigned int b = __float_as_uint(f);
  return (b + 0x7FFFu + ((b>>16)&1u)) >> 16;
}

// ---------------- temporal stage 1: partial Grams per c-slice ----------------
__global__ __launch_bounds__(256) void k_t1(const float* __restrict__ x, float* __restrict__ wsG){
  const int bx = blockIdx.x;
  const int b = bx / 112;
  const int ph = (bx % 112) / 16;
  const int slice = bx & 15;
  const int c0 = slice * 16;
  const int tid = threadIdx.x;

  __shared__ float lds[8*16*116];   // [t][c][116-padded stripe of 112 floats]
  const float4* x4 = reinterpret_cast<const float4*>(x);

  #pragma unroll
  for (int t=0;t<8;t++){
    const int base = ((b*8+t)*256 + c0)*196 + ph*28;
    {
      const int f = tid, c = f/28, m = f%28;
      *reinterpret_cast<float4*>(&lds[(t*16+c)*116 + m*4]) = x4[base + c*196 + m];
    }
    if (tid < 192){
      const int f = 256+tid, c = f/28, m = f%28;
      *reinterpret_cast<float4*>(&lds[(t*16+c)*116 + m*4]) = x4[base + c*196 + m];
    }
  }
  __syncthreads();

  const int pw   = tid >> 5;        // 0..6 valid; group 7 is idle-compute
  const int slot = tid & 31;
  const int c    = slot >> 1;
  const int p1b  = (slot & 1) * 2;

  float v[8][8];
  #pragma unroll
  for (int t=0;t<8;t++){
    const float* p = &lds[(t*16+c)*116 + p1b*28 + pw*4];
    const float4 a  = *reinterpret_cast<const float4*>(p);
    const float4 b2 = *reinterpret_cast<const float4*>(p + 28);
    v[t][0]=a.x;  v[t][1]=a.y;  v[t][2]=a.z;  v[t][3]=a.w;
    v[t][4]=b2.x; v[t][5]=b2.y; v[t][6]=b2.z; v[t][7]=b2.w;
  }

  float Au[36], sm[8];
  #pragma unroll
  for (int a2=0;a2<8;a2++){
    float s0 = 0.f;
    #pragma unroll
    for (int e=0;e<8;e++) s0 += v[a2][e];
    sm[a2] = s0;
    #pragma unroll
    for (int b2=a2;b2<8;b2++){
      float s = 0.f;
      #pragma unroll
      for (int e=0;e<8;e++) s += v[a2][e]*v[b2][e];
      Au[IDX36(a2,b2)] = s;
    }
  }
  #pragma unroll
  for (int i=0;i<36;i++) Au[i] = wsum32(Au[i]);
  #pragma unroll
  for (int t=0;t<8;t++) sm[t] = wsum32(sm[t]);

  if (slot == 0 && pw < 7){
    const int base = ((b*49 + ph*7 + pw)*16 + slice)*44;
    #pragma unroll
    for (int i=0;i<36;i++) wsG[base+i] = Au[i];
    #pragma unroll
    for (int t=0;t<8;t++)  wsG[base+36+t] = sm[t];
  }
}

// ---------------- temporal stage 2: reduce slices, softmax -> W, cc ----------------
__global__ __launch_bounds__(64) void k_t2(const float* __restrict__ wsG, float* __restrict__ wsWt){
  const int seq = blockIdx.x;
  const int lane = threadIdx.x;
  __shared__ float red[44];
  if (lane < 44){
    float a = 0.f;
    #pragma unroll
    for (int s=0;s<16;s++) a += wsG[(seq*16+s)*44 + lane];
    red[lane] = a;
  }
  __syncthreads();
  if (lane < 8){
    const int i = lane;
    float Ar[36], mean[8], rstd[8];
    #pragma unroll
    for (int k=0;k<36;k++) Ar[k] = red[k];
    #pragma unroll
    for (int t=0;t<8;t++){
      const float sv = red[36+t];
      mean[t] = sv * (1.f/4096.f);
      const float var = Ar[IDX36(t,t)] * (1.f/4096.f) - mean[t]*mean[t];
      rstd[t] = rsqrtf(var + 1e-5f);
    }
    #define GV(a,b) ((((a)<8)&&((b)<8)) ? (rstd[(a)]*rstd[(b)]*(Ar[((a)<=(b))?IDX36((a),(b)):IDX36((b),(a))] - 4096.f*mean[(a)]*mean[(b)])) : 0.f)
    float l[8]; float mx = -1e30f;
    #pragma unroll
    for (int j=0;j<8;j++){
      const float sij = GV(i+1,j+1) - GV(i+1,j) - GV(i,j+1) + GV(i,j);
      l[j] = sij * (1.f/64.f);
      mx = fmaxf(mx, l[j]);
    }
    float ss = 0.f;
    #pragma unroll
    for (int j=0;j<8;j++){ l[j] = __expf(l[j]-mx); ss += l[j]; }
    const float inv = 1.f/ss;
    float cc = 0.f;
    #pragma unroll
    for (int k2=0;k2<8;k2++){
      const float q = (((k2>=1)? l[k2-1] : 0.f) - l[k2]) * inv;
      const float wv2 = q * rstd[k2];
      wsWt[seq*72 + i*8 + k2] = wv2;
      cc -= wv2 * mean[k2];
    }
    wsWt[seq*72 + 64 + i] = cc;
    #undef GV
  }
}

// ---------------- temporal stage 3: recombine + write y1 ----------------
__global__ __launch_bounds__(256) void k_t3(const float* __restrict__ x, const float* __restrict__ wsWt,
                                            float* __restrict__ y1){
  const int bx = blockIdx.x;
  const int b = bx / 112;
  const int ph = (bx % 112) / 16;
  const int slice = bx & 15;
  const int c0 = slice * 16;
  const int tid = threadIdx.x;

  __shared__ float Wl[7][72];
  for (int idx=tid; idx<504; idx+=256)
    Wl[idx/72][idx%72] = wsWt[(b*49 + ph*7 + idx/72)*72 + idx%72];
  __syncthreads();

  const float4* x4 = reinterpret_cast<const float4*>(x);
  float4* y4 = reinterpret_cast<float4*>(y1);

  #pragma unroll
  for (int fi=0; fi<2; fi++){
    const int f = fi*256 + tid;
    if (f < 448){
      const int c = f/28, m = f%28, pw = m%7, p1 = m/7;
      float4 v[8];
      #pragma unroll
      for (int t=0;t<8;t++) v[t] = x4[((b*8+t)*256 + c0+c)*196 + ph*28 + m];
      const float* W = Wl[pw];
      const int pp = ph*7 + pw;
      #pragma unroll
      for (int i=0;i<8;i++){
        const float ci = W[64+i];
        float4 o;
        o.x = v[i].x + ci; o.y = v[i].y + ci; o.z = v[i].z + ci; o.w = v[i].w + ci;
        #pragma unroll
        for (int j=0;j<8;j++){
          const float w = W[i*8+j];
          o.x += w*v[j].x; o.y += w*v[j].y; o.z += w*v[j].z; o.w += w*v[j].w;
        }
        y4[((b*8+i)*49 + pp)*1024 + (c0+c)*4 + p1] = o;
      }
    }
  }
}

// ---------------- spatial stage: Gram partials via split-bf16 MFMA ----------------
__global__ __launch_bounds__(256,2) void k_s1(const float* __restrict__ y1, float* __restrict__ wsA){
  const int bt = blockIdx.x >> 2;
  const int slice = blockIdx.x & 3;
  const int tid = threadIdx.x;
  const int wave = tid >> 6, lane = tid & 63;

  __shared__ unsigned short Ah[64*136];
  __shared__ unsigned short Al[64*136];
  __shared__ float red[64*52];

  for (int i=tid; i<64*52; i+=256) red[i] = 0.f;

  f32x16 acc00, acc01, acc11;
  #pragma unroll
  for (int i=0;i<16;i++){ acc00[i]=0.f; acc01[i]=0.f; acc11[i]=0.f; }

  const float4* yb4 = reinterpret_cast<const float4*>(y1 + bt*49*4096 + slice*1024);
  const int rgrp = tid >> 5;            // 0..7: row sub-group
  const int col4 = tid & 31;            // float4 column within 128-float chunk
  const int r0 = lane & 31;
  const int koff = (lane >> 5) * 8;

#define ISSUE_CH(pf, ch) { \
  _Pragma("unroll") \
  for (int i=0;i<7;i++) pf[i] = yb4[(i*8 + rgrp)*1024 + (ch)*32 + col4]; }

#define CW_CH(pf) { \
  _Pragma("unroll") \
  for (int i=0;i<8;i++){ \
    unsigned int h01,h23,l01,l23; \
    if (i==7){ h01=0u; h23=0u; l01=0u; l23=0u; } \
    else { \
      const float4 v = pf[i]; \
      const unsigned int u0=__float_as_uint(v.x), u1=__float_as_uint(v.y); \
      const unsigned int u2=__float_as_uint(v.z), u3=__float_as_uint(v.w); \
      const float l0 = v.x-__uint_as_float(u0&0xFFFF0000u); \
      const float l1 = v.y-__uint_as_float(u1&0xFFFF0000u); \
      const float l2 = v.z-__uint_as_float(u2&0xFFFF0000u); \
      const float l3 = v.w-__uint_as_float(u3&0xFFFF0000u); \
      h01 = (u0>>16)|(u1&0xFFFF0000u); h23 = (u2>>16)|(u3&0xFFFF0000u); \
      l01 = rne_bf16(l0)|(rne_bf16(l1)<<16); l23 = rne_bf16(l2)|(rne_bf16(l3)<<16); \
      if (i==6){ \
        const bool valid = (rgrp==0); const bool ones = (rgrp==1); \
        h01 = valid ? h01 : (ones ? 0x3F803F80u : 0u); \
        h23 = valid ? h23 : (ones ? 0x3F803F80u : 0u); \
        l01 = valid ? l01 : 0u; l23 = valid ? l23 : 0u; \
      } \
    } \
    const int wb = (i*8+rgrp)*136 + col4*4; \
    *reinterpret_cast<uint2*>(&Ah[wb]) = make_uint2(h01,h23); \
    *reinterpret_cast<uint2*>(&Al[wb]) = make_uint2(l01,l23); \
  } }

#define MFMA_CH() { \
  _Pragma("unroll") \
  for (int kk=0;kk<2;kk++){ \
    const int kw = (wave + kk*4)*16; \
    const bf16x8 f0h = *reinterpret_cast<const bf16x8*>(&Ah[ r0     *136 + kw + koff]); \
    const bf16x8 f0l = *reinterpret_cast<const bf16x8*>(&Al[ r0     *136 + kw + koff]); \
    const bf16x8 f1h = *reinterpret_cast<const bf16x8*>(&Ah[(32+r0)*136 + kw + koff]); \
    const bf16x8 f1l = *reinterpret_cast<const bf16x8*>(&Al[(32+r0)*136 + kw + koff]); \
    acc00 = __builtin_amdgcn_mfma_f32_32x32x16_bf16(f0h, f0h, acc00, 0,0,0); \
    acc00 = __builtin_amdgcn_mfma_f32_32x32x16_bf16(f0h, f0l, acc00, 0,0,0); \
    acc00 = __builtin_amdgcn_mfma_f32_32x32x16_bf16(f0l, f0h, acc00, 0,0,0); \
    acc01 = __builtin_amdgcn_mfma_f32_32x32x16_bf16(f0h, f1h, acc01, 0,0,0); \
    acc01 = __builtin_amdgcn_mfma_f32_32x32x16_bf16(f0h, f1l, acc01, 0,0,0); \
    acc01 = __builtin_amdgcn_mfma_f32_32x32x16_bf16(f0l, f1h, acc01, 0,0,0); \
    acc11 = __builtin_amdgcn_mfma_f32_32x32x16_bf16(f1h, f1h, acc11, 0,0,0); \
    acc11 = __builtin_amdgcn_mfma_f32_32x32x16_bf16(f1h, f1l, acc11, 0,0,0); \
    acc11 = __builtin_amdgcn_mfma_f32_32x32x16_bf16(f1l, f1h, acc11, 0,0,0); \
  } }

  float4 pfA[7], pfB[7];
  ISSUE_CH(pfA, 0);
  #pragma unroll
  for (int ch=0; ch<8; ch+=2){
    if (ch+1<8) ISSUE_CH(pfB, ch+1);
    __syncthreads();                 // prev MFMA done reading LDS
    CW_CH(pfA);                      // waits only pfA's loads (older)
    __syncthreads();
    MFMA_CH();
    if (ch+2<8) ISSUE_CH(pfA, ch+2);
    __syncthreads();
    CW_CH(pfB);
    __syncthreads();
    MFMA_CH();
  }
  __syncthreads();

  // cross-wave reduce (upper tiles): C layout col=lane&31, row=(reg&3)+8*(reg>>2)+4*(lane>>5)
  const int ccol = lane & 31;
  const int rbase = 4*(lane>>5);
  #pragma unroll
  for (int q2=0;q2<16;q2++){
    const int rr = (q2&3) + 8*(q2>>2) + rbase;
    atomicAdd(&red[ rr    *52 + ccol     ], acc00[q2]);
    atomicAdd(&red[ rr    *52 + 32 + ccol], acc01[q2]);
    atomicAdd(&red[(rr+32)*52 + 32 + ccol], acc11[q2]);
  }
  __syncthreads();
  float* wp = wsA + blockIdx.x * 2500;
  for (int idx=tid; idx<2500; idx+=256){
    const int i2 = idx/50, j2 = idx%50;
    wp[idx] = (i2>=32 && j2<32) ? red[j2*52+i2] : red[i2*52+j2];
  }
#undef ISSUE_CH
#undef CW_CH
#undef MFMA_CH
}

// ---------------- spatial stage: softmax -> WT (+I folded, padded 52), c ----------------
__global__ __launch_bounds__(256) void k_s2(const float* __restrict__ wsA, float* __restrict__ wsWT, float* __restrict__ wsC){
  const int bt = blockIdx.x;
  const int tid = threadIdx.x;
  __shared__ float A[2500];
  __shared__ float m[49], r[49];
  for (int idx=tid; idx<2548; idx+=256) wsWT[bt*2548+idx] = 0.f;
  for (int idx=tid; idx<2500; idx+=256){
    float v = 0.f;
    #pragma unroll
    for (int sl=0; sl<4; sl++) v += wsA[(bt*4+sl)*2500 + idx];
    A[idx] = v;
  }
  __syncthreads();
  if (tid < 49){
    const float mm = A[49*50+tid] * (1.f/4096.f);        // row 49 = ones row -> sums
    const float var = A[tid*50+tid] * (1.f/4096.f) - mm*mm;
    m[tid]=mm; r[tid]=rsqrtf(var+1e-5f);
  }
  __syncthreads();
  const int wv = tid>>6, lane = tid&63;
  for (int i=wv; i<49; i+=4){
    const float ri = r[i], mi = m[i];
    float rv=0.f, mv=0.f, L=-1e30f;
    if (lane < 49){
      rv = r[lane]; mv = m[lane];
      L = ri*rv*(A[i*50+lane] - 4096.f*mi*mv) * (1.f/64.f);
    }
    float mx = L;
    #pragma unroll
    for (int off=32; off; off>>=1) mx = fmaxf(mx, __shfl_xor(mx, off));
    const float p = (lane<49) ? __expf(L-mx) : 0.f;
    const float ss = wsum64(p);
    const float Wv = (p/ss)*rv;
    if (lane < 49) wsWT[bt*2548 + lane*52 + i] = Wv + ((lane==i) ? 1.f : 0.f);
    const float cp = wsum64(-Wv*mv);
    if (lane == 0) wsC[bt*49+i] = cp;
  }
}

// ---------------- spatial stage: recombine + scatter back to x layout ----------------
// 1024 blocks = 128 bt * 8 e-chunks of 512; float2 acc (98 VGPR) -> fits 128-cap at 4 waves/SIMD.
// W rows read via wave-uniform scalar loads (SGPR path) -> zero VALU/DS cost for weights.
__global__ __launch_bounds__(256,4) void k_s3(const float* __restrict__ y1, const float* __restrict__ wsWT,
                                              const float* __restrict__ wsC, float* __restrict__ out){
  const int bt = blockIdx.x >> 3;
  const int chunk = blockIdx.x & 7;
  const int tid = threadIdx.x;
  const int e0 = chunk*512 + tid*2;

  float2 acc[49];
  #pragma unroll
  for (int i=0;i<49;i++){ acc[i].x=0.f; acc[i].y=0.f; }

  const float* yb = y1 + bt*49*4096;
  const float* Wb = wsWT + bt*2548;

  for (int j=0;j<49;++j){
    const float2 v = *reinterpret_cast<const float2*>(yb + j*4096 + e0);
    const float* wr = Wb + __builtin_amdgcn_readfirstlane(j*52);   // uniform -> s_load
    #pragma unroll
    for (int i=0;i<49;i++){
      const float w = wr[i];
      acc[i].x += w*v.x; acc[i].y += w*v.y;
    }
  }

  const float* cb = wsC + bt*49;
  const int c  = e0 >> 4;
  const int p1 = (e0 >> 2) & 3;
  const int p2 = e0 & 3;           // 0 or 2
  float* ob = out + bt*200704 + c*784 + p1*28 + p2;
  #pragma unroll
  for (int i=0;i<49;i++){
    const float ci = cb[i];
    float2 o;
    o.x = acc[i].x + ci; o.y = acc[i].y + ci;
    *reinterpret_cast<float2*>(ob + (i/7)*112 + (i%7)*4) = o;
  }
}

extern "C" void kernel_launch(void* const* d_in, const int* in_sizes, int n_in,
                              void* d_out, int out_size, void* d_ws, size_t ws_size,
                              hipStream_t stream) {
  const float* x = (const float*)d_in[0];
  float* out = (float*)d_out;
  float* ws  = (float*)d_ws;
  float* y1   = ws;                     // 25,690,112 floats (102.8 MB)
  float* wsA  = y1 + 25690112;          // 512*2500 = 1,280,000 floats
  float* wsWT = wsA + 512*2500;         // 128*2548 = 326,144 floats (W^T + I, padded 52)
  float* wsC  = wsWT + 128*2548;        // 128*49   -> total ~109.2 MB
  // overlay (dead before k_s1 writes wsA): temporal partials + per-seq W
  float* wsG  = wsA;                    // 784*16*44 = 551,936 floats
  float* wsWt = wsA + 551936;           // 784*72   =  56,448 floats (fits in wsA)
  hipLaunchKernelGGL(k_t1, dim3(1792), dim3(256), 0, stream, x, wsG);
  hipLaunchKernelGGL(k_t2, dim3(784),  dim3(64),  0, stream, wsG, wsWt);
  hipLaunchKernelGGL(k_t3, dim3(1792), dim3(256), 0, stream, x, wsWt, y1);
  hipLaunchKernelGGL(k_s1, dim3(512),  dim3(256), 0, stream, y1, wsA);
  hipLaunchKernelGGL(k_s2, dim3(128),  dim3(256), 0, stream, wsA, wsWT, wsC);
  hipLaunchKernelGGL(k_s3, dim3(1024), dim3(256), 0, stream, y1, wsWT, wsC, out);
}

// Round 7
// 197.732 us; speedup vs baseline: 1.9718x; 1.0672x over previous
//
#include <hip/hip_runtime.h>

// x: (128, 256, 28, 28) fp32.  b=16, t=8, c=256, h=w=28, p=4, ph=pw=7, e=4096.
// y1 (ws): [bt][pp][e'], e' = c*16 + p1*4 + p2 (LN/attn are e-permutation invariant).

#define IDX36(a,b) ((((a)*8)+(b))-((((a)*((a)+1)))/2))

typedef __attribute__((ext_vector_type(8)))  short bf16x8;   // 8 bf16 (4 VGPRs)
typedef __attribute__((ext_vector_type(16))) float f32x16;   // 32x32 MFMA acc

__device__ __forceinline__ float wsum64(float v){
  #pragma unroll
  for (int off=32; off; off>>=1) v += __shfl_xor(v, off);
  return v;
}
__device__ __forceinline__ float wsum32(float v){
  #pragma unroll
  for (int off=16; off; off>>=1) v += __shfl_xor(v, off);
  return v;
}
__device__ __forceinline__ unsigned int rne_bf16(float f){
  unsigned int b = __float_as_uint(f);
  return (b + 0x7FFFu + ((b>>16)&1u)) >> 16;
}

// ---------------- temporal stage 1: partial Grams per c-slice ----------------
__global__ __launch_bounds__(256) void k_t1(const float* __restrict__ x, float* __restrict__ wsG){
  const int bx = blockIdx.x;
  const int b = bx / 112;
  const int ph = (bx % 112) / 16;
  const int slice = bx & 15;
  const int c0 = slice * 16;
  const int tid = threadIdx.x;

  __shared__ float lds[8*16*116];   // [t][c][116-padded stripe of 112 floats]
  const float4* x4 = reinterpret_cast<const float4*>(x);

  #pragma unroll
  for (int t=0;t<8;t++){
    const int base = ((b*8+t)*256 + c0)*196 + ph*28;
    {
      const int f = tid, c = f/28, m = f%28;
      *reinterpret_cast<float4*>(&lds[(t*16+c)*116 + m*4]) = x4[base + c*196 + m];
    }
    if (tid < 192){
      const int f = 256+tid, c = f/28, m = f%28;
      *reinterpret_cast<float4*>(&lds[(t*16+c)*116 + m*4]) = x4[base + c*196 + m];
    }
  }
  __syncthreads();

  const int pw   = tid >> 5;        // 0..6 valid; group 7 is idle-compute
  const int slot = tid & 31;
  const int c    = slot >> 1;
  const int p1b  = (slot & 1) * 2;

  float v[8][8];
  #pragma unroll
  for (int t=0;t<8;t++){
    const float* p = &lds[(t*16+c)*116 + p1b*28 + pw*4];
    const float4 a  = *reinterpret_cast<const float4*>(p);
    const float4 b2 = *reinterpret_cast<const float4*>(p + 28);
    v[t][0]=a.x;  v[t][1]=a.y;  v[t][2]=a.z;  v[t][3]=a.w;
    v[t][4]=b2.x; v[t][5]=b2.y; v[t][6]=b2.z; v[t][7]=b2.w;
  }

  float Au[36], sm[8];
  #pragma unroll
  for (int a2=0;a2<8;a2++){
    float s0 = 0.f;
    #pragma unroll
    for (int e=0;e<8;e++) s0 += v[a2][e];
    sm[a2] = s0;
    #pragma unroll
    for (int b2=a2;b2<8;b2++){
      float s = 0.f;
      #pragma unroll
      for (int e=0;e<8;e++) s += v[a2][e]*v[b2][e];
      Au[IDX36(a2,b2)] = s;
    }
  }
  #pragma unroll
  for (int i=0;i<36;i++) Au[i] = wsum32(Au[i]);
  #pragma unroll
  for (int t=0;t<8;t++) sm[t] = wsum32(sm[t]);

  if (slot == 0 && pw < 7){
    const int base = ((b*49 + ph*7 + pw)*16 + slice)*44;
    #pragma unroll
    for (int i=0;i<36;i++) wsG[base+i] = Au[i];
    #pragma unroll
    for (int t=0;t<8;t++)  wsG[base+36+t] = sm[t];
  }
}

// ---------------- temporal stage 2: reduce slices, softmax -> W, cc ----------------
__global__ __launch_bounds__(64) void k_t2(const float* __restrict__ wsG, float* __restrict__ wsWt){
  const int seq = blockIdx.x;
  const int lane = threadIdx.x;
  __shared__ float red[44];
  if (lane < 44){
    float a = 0.f;
    #pragma unroll
    for (int s=0;s<16;s++) a += wsG[(seq*16+s)*44 + lane];
    red[lane] = a;
  }
  __syncthreads();
  if (lane < 8){
    const int i = lane;
    float Ar[36], mean[8], rstd[8];
    #pragma unroll
    for (int k=0;k<36;k++) Ar[k] = red[k];
    #pragma unroll
    for (int t=0;t<8;t++){
      const float sv = red[36+t];
      mean[t] = sv * (1.f/4096.f);
      const float var = Ar[IDX36(t,t)] * (1.f/4096.f) - mean[t]*mean[t];
      rstd[t] = rsqrtf(var + 1e-5f);
    }
    #define GV(a,b) ((((a)<8)&&((b)<8)) ? (rstd[(a)]*rstd[(b)]*(Ar[((a)<=(b))?IDX36((a),(b)):IDX36((b),(a))] - 4096.f*mean[(a)]*mean[(b)])) : 0.f)
    float l[8]; float mx = -1e30f;
    #pragma unroll
    for (int j=0;j<8;j++){
      const float sij = GV(i+1,j+1) - GV(i+1,j) - GV(i,j+1) + GV(i,j);
      l[j] = sij * (1.f/64.f);
      mx = fmaxf(mx, l[j]);
    }
    float ss = 0.f;
    #pragma unroll
    for (int j=0;j<8;j++){ l[j] = __expf(l[j]-mx); ss += l[j]; }
    const float inv = 1.f/ss;
    float cc = 0.f;
    #pragma unroll
    for (int k2=0;k2<8;k2++){
      const float q = (((k2>=1)? l[k2-1] : 0.f) - l[k2]) * inv;
      const float wv2 = q * rstd[k2];
      wsWt[seq*72 + i*8 + k2] = wv2;
      cc -= wv2 * mean[k2];
    }
    wsWt[seq*72 + 64 + i] = cc;
    #undef GV
  }
}

// ---------------- temporal stage 3: recombine + write y1 ----------------
__global__ __launch_bounds__(256) void k_t3(const float* __restrict__ x, const float* __restrict__ wsWt,
                                            float* __restrict__ y1){
  const int bx = blockIdx.x;
  const int b = bx / 112;
  const int ph = (bx % 112) / 16;
  const int slice = bx & 15;
  const int c0 = slice * 16;
  const int tid = threadIdx.x;

  __shared__ float Wl[7][72];
  for (int idx=tid; idx<504; idx+=256)
    Wl[idx/72][idx%72] = wsWt[(b*49 + ph*7 + idx/72)*72 + idx%72];
  __syncthreads();

  const float4* x4 = reinterpret_cast<const float4*>(x);
  float4* y4 = reinterpret_cast<float4*>(y1);

  #pragma unroll
  for (int fi=0; fi<2; fi++){
    const int f = fi*256 + tid;
    if (f < 448){
      const int c = f/28, m = f%28, pw = m%7, p1 = m/7;
      float4 v[8];
      #pragma unroll
      for (int t=0;t<8;t++) v[t] = x4[((b*8+t)*256 + c0+c)*196 + ph*28 + m];
      const float* W = Wl[pw];
      const int pp = ph*7 + pw;
      #pragma unroll
      for (int i=0;i<8;i++){
        const float ci = W[64+i];
        float4 o;
        o.x = v[i].x + ci; o.y = v[i].y + ci; o.z = v[i].z + ci; o.w = v[i].w + ci;
        #pragma unroll
        for (int j=0;j<8;j++){
          const float w = W[i*8+j];
          o.x += w*v[j].x; o.y += w*v[j].y; o.z += w*v[j].z; o.w += w*v[j].w;
        }
        y4[((b*8+i)*49 + pp)*1024 + (c0+c)*4 + p1] = o;
      }
    }
  }
}

// ---------------- spatial stage: Gram partials via split-bf16 MFMA ----------------
__global__ __launch_bounds__(256,2) void k_s1(const float* __restrict__ y1, float* __restrict__ wsA){
  const int bt = blockIdx.x >> 2;
  const int slice = blockIdx.x & 3;
  const int tid = threadIdx.x;
  const int wave = tid >> 6, lane = tid & 63;

  __shared__ unsigned short Ah[64*136];
  __shared__ unsigned short Al[64*136];
  __shared__ float red[64*52];

  for (int i=tid; i<64*52; i+=256) red[i] = 0.f;

  f32x16 acc00, acc01, acc11;
  #pragma unroll
  for (int i=0;i<16;i++){ acc00[i]=0.f; acc01[i]=0.f; acc11[i]=0.f; }

  const float4* yb4 = reinterpret_cast<const float4*>(y1 + bt*49*4096 + slice*1024);
  const int rgrp = tid >> 5;            // 0..7: row sub-group
  const int col4 = tid & 31;            // float4 column within 128-float chunk
  const int r0 = lane & 31;
  const int koff = (lane >> 5) * 8;

#define ISSUE_CH(pf, ch) { \
  _Pragma("unroll") \
  for (int i=0;i<7;i++) pf[i] = yb4[(i*8 + rgrp)*1024 + (ch)*32 + col4]; }

#define CW_CH(pf) { \
  _Pragma("unroll") \
  for (int i=0;i<8;i++){ \
    unsigned int h01,h23,l01,l23; \
    if (i==7){ h01=0u; h23=0u; l01=0u; l23=0u; } \
    else { \
      const float4 v = pf[i]; \
      const unsigned int u0=__float_as_uint(v.x), u1=__float_as_uint(v.y); \
      const unsigned int u2=__float_as_uint(v.z), u3=__float_as_uint(v.w); \
      const float l0 = v.x-__uint_as_float(u0&0xFFFF0000u); \
      const float l1 = v.y-__uint_as_float(u1&0xFFFF0000u); \
      const float l2 = v.z-__uint_as_float(u2&0xFFFF0000u); \
      const float l3 = v.w-__uint_as_float(u3&0xFFFF0000u); \
      h01 = (u0>>16)|(u1&0xFFFF0000u); h23 = (u2>>16)|(u3&0xFFFF0000u); \
      l01 = rne_bf16(l0)|(rne_bf16(l1)<<16); l23 = rne_bf16(l2)|(rne_bf16(l3)<<16); \
      if (i==6){ \
        const bool valid = (rgrp==0); const bool ones = (rgrp==1); \
        h01 = valid ? h01 : (ones ? 0x3F803F80u : 0u); \
        h23 = valid ? h23 : (ones ? 0x3F803F80u : 0u); \
        l01 = valid ? l01 : 0u; l23 = valid ? l23 : 0u; \
      } \
    } \
    const int wb = (i*8+rgrp)*136 + col4*4; \
    *reinterpret_cast<uint2*>(&Ah[wb]) = make_uint2(h01,h23); \
    *reinterpret_cast<uint2*>(&Al[wb]) = make_uint2(l01,l23); \
  } }

#define MFMA_CH() { \
  _Pragma("unroll") \
  for (int kk=0;kk<2;kk++){ \
    const int kw = (wave + kk*4)*16; \
    const bf16x8 f0h = *reinterpret_cast<const bf16x8*>(&Ah[ r0     *136 + kw + koff]); \
    const bf16x8 f0l = *reinterpret_cast<const bf16x8*>(&Al[ r0     *136 + kw + koff]); \
    const bf16x8 f1h = *reinterpret_cast<const bf16x8*>(&Ah[(32+r0)*136 + kw + koff]); \
    const bf16x8 f1l = *reinterpret_cast<const bf16x8*>(&Al[(32+r0)*136 + kw + koff]); \
    acc00 = __builtin_amdgcn_mfma_f32_32x32x16_bf16(f0h, f0h, acc00, 0,0,0); \
    acc00 = __builtin_amdgcn_mfma_f32_32x32x16_bf16(f0h, f0l, acc00, 0,0,0); \
    acc00 = __builtin_amdgcn_mfma_f32_32x32x16_bf16(f0l, f0h, acc00, 0,0,0); \
    acc01 = __builtin_amdgcn_mfma_f32_32x32x16_bf16(f0h, f1h, acc01, 0,0,0); \
    acc01 = __builtin_amdgcn_mfma_f32_32x32x16_bf16(f0h, f1l, acc01, 0,0,0); \
    acc01 = __builtin_amdgcn_mfma_f32_32x32x16_bf16(f0l, f1h, acc01, 0,0,0); \
    acc11 = __builtin_amdgcn_mfma_f32_32x32x16_bf16(f1h, f1h, acc11, 0,0,0); \
    acc11 = __builtin_amdgcn_mfma_f32_32x32x16_bf16(f1h, f1l, acc11, 0,0,0); \
    acc11 = __builtin_amdgcn_mfma_f32_32x32x16_bf16(f1l, f1h, acc11, 0,0,0); \
  } }

  float4 pfA[7], pfB[7];
  ISSUE_CH(pfA, 0);
  #pragma unroll
  for (int ch=0; ch<8; ch+=2){
    if (ch+1<8) ISSUE_CH(pfB, ch+1);
    __syncthreads();                 // prev MFMA done reading LDS
    CW_CH(pfA);                      // waits only pfA's loads (older)
    __syncthreads();
    MFMA_CH();
    if (ch+2<8) ISSUE_CH(pfA, ch+2);
    __syncthreads();
    CW_CH(pfB);
    __syncthreads();
    MFMA_CH();
  }
  __syncthreads();

  // cross-wave reduce (upper tiles): C layout col=lane&31, row=(reg&3)+8*(reg>>2)+4*(lane>>5)
  const int ccol = lane & 31;
  const int rbase = 4*(lane>>5);
  #pragma unroll
  for (int q2=0;q2<16;q2++){
    const int rr = (q2&3) + 8*(q2>>2) + rbase;
    atomicAdd(&red[ rr    *52 + ccol     ], acc00[q2]);
    atomicAdd(&red[ rr    *52 + 32 + ccol], acc01[q2]);
    atomicAdd(&red[(rr+32)*52 + 32 + ccol], acc11[q2]);
  }
  __syncthreads();
  float* wp = wsA + blockIdx.x * 2500;
  for (int idx=tid; idx<2500; idx+=256){
    const int i2 = idx/50, j2 = idx%50;
    wp[idx] = (i2>=32 && j2<32) ? red[j2*52+i2] : red[i2*52+j2];
  }
#undef ISSUE_CH
#undef CW_CH
#undef MFMA_CH
}

// ---------------- spatial stage: softmax -> WT (+I folded, padded 52), c ----------------
__global__ __launch_bounds__(256) void k_s2(const float* __restrict__ wsA, float* __restrict__ wsWT, float* __restrict__ wsC){
  const int bt = blockIdx.x;
  const int tid = threadIdx.x;
  __shared__ float A[2500];
  __shared__ float m[49], r[49];
  for (int idx=tid; idx<2548; idx+=256) wsWT[bt*2548+idx] = 0.f;
  for (int idx=tid; idx<2500; idx+=256){
    float v = 0.f;
    #pragma unroll
    for (int sl=0; sl<4; sl++) v += wsA[(bt*4+sl)*2500 + idx];
    A[idx] = v;
  }
  __syncthreads();
  if (tid < 49){
    const float mm = A[49*50+tid] * (1.f/4096.f);        // row 49 = ones row -> sums
    const float var = A[tid*50+tid] * (1.f/4096.f) - mm*mm;
    m[tid]=mm; r[tid]=rsqrtf(var+1e-5f);
  }
  __syncthreads();
  const int wv = tid>>6, lane = tid&63;
  for (int i=wv; i<49; i+=4){
    const float ri = r[i], mi = m[i];
    float rv=0.f, mv=0.f, L=-1e30f;
    if (lane < 49){
      rv = r[lane]; mv = m[lane];
      L = ri*rv*(A[i*50+lane] - 4096.f*mi*mv) * (1.f/64.f);
    }
    float mx = L;
    #pragma unroll
    for (int off=32; off; off>>=1) mx = fmaxf(mx, __shfl_xor(mx, off));
    const float p = (lane<49) ? __expf(L-mx) : 0.f;
    const float ss = wsum64(p);
    const float Wv = (p/ss)*rv;
    if (lane < 49) wsWT[bt*2548 + lane*52 + i] = Wv + ((lane==i) ? 1.f : 0.f);
    const float cp = wsum64(-Wv*mv);
    if (lane == 0) wsC[bt*49+i] = cp;
  }
}

// ---------------- spatial stage: recombine via split-bf16 MFMA + scatter to x layout ----------------
// O = (W+I)*Y + c as MFMA GEMM: M=49(pad64) rows, K=49(pad64, c folded at j=49 vs ones-row),
// N=4096 e-cols. W-frags hoisted to regs once; per-wave private Y^T LDS tile, barrier-free
// staging with register prefetch. grid = 128 bt * 4 chunks of 1024 cols; 4 waves * 8 tiles.
__global__ __launch_bounds__(256,2) void k_s3(const float* __restrict__ y1, const float* __restrict__ wsWT,
                                              const float* __restrict__ wsC, float* __restrict__ out){
  const int bt = blockIdx.x >> 2;
  const int chunk = blockIdx.x & 3;
  const int tid = threadIdx.x;
  const int wave = tid >> 6, lane = tid & 63;

  __shared__ unsigned short Wh[64*68], Wlo[64*68];
  __shared__ unsigned short Yh[4][32*68], Ylo[4][32*68];

  // ---- stage W (+I already folded in wsWT); c folded as column j=49 ----
  for (int idx=tid; idx<64*64; idx+=256){
    const int i = idx>>6, j = idx&63;
    float v = 0.f;
    if (i < 49){
      if (j < 49)       v = wsWT[bt*2548 + j*52 + i];   // W[i][j]+I
      else if (j == 49) v = wsC[bt*49 + i];             // c[i]
    }
    const unsigned int u = __float_as_uint(v);
    const float lo = v - __uint_as_float(u & 0xFFFF0000u);
    Wh [i*68+j] = (unsigned short)(u>>16);
    Wlo[i*68+j] = (unsigned short)rne_bf16(lo);
  }
  // ---- init per-wave Y pad columns j=49..63 (ones at j=49; never overwritten) ----
  unsigned short* yh = &Yh[wave][0];
  unsigned short* yl = &Ylo[wave][0];
  for (int idx=lane; idx<32*16; idx+=64){
    const int e = idx>>4, jj = idx&15;       // j = 48+jj; skip jj==0 (real data col 48)
    if (jj > 0){
      yh[e*68 + 48 + jj] = (jj==1) ? 0x3F80 : 0;   // bf16(1.0) at j=49
      yl[e*68 + 48 + jj] = 0;
    }
  }
  __syncthreads();

  // ---- hoist W fragments: rows (lane&31) and 32+(lane&31), all 4 k-steps ----
  const int r0 = lane & 31;
  const int koff = (lane >> 5) * 8;
  bf16x8 A0h[4], A0l[4], A1h[4], A1l[4];
  #pragma unroll
  for (int kk=0;kk<4;kk++){
    const int off = kk*16 + koff;
    A0h[kk] = *reinterpret_cast<const bf16x8*>(&Wh [ r0     *68 + off]);
    A0l[kk] = *reinterpret_cast<const bf16x8*>(&Wlo[ r0     *68 + off]);
    A1h[kk] = *reinterpret_cast<const bf16x8*>(&Wh [(32+r0)*68 + off]);
    A1l[kk] = *reinterpret_cast<const bf16x8*>(&Wlo[(32+r0)*68 + off]);
  }

  const float4* yb4 = reinterpret_cast<const float4*>(y1 + bt*200704 + chunk*1024);
  float* ob_base = out + bt*200704;

#define S3_LOAD(pf, t) { \
  _Pragma("unroll") \
  for (int p=0;p<7;p++){ \
    const int idx = p*64 + lane; const int j = idx>>3, e4 = idx&7; \
    pf[p] = make_float4(0.f,0.f,0.f,0.f); \
    if (j < 49) pf[p] = yb4[j*1024 + ((t)*4+wave)*8 + e4]; \
  } }

#define S3_WRITE(pf) { \
  _Pragma("unroll") \
  for (int p=0;p<7;p++){ \
    const int idx = p*64 + lane; const int j = idx>>3, e4 = idx&7; \
    if (j < 49){ \
      const float vv[4] = {pf[p].x, pf[p].y, pf[p].z, pf[p].w}; \
      _Pragma("unroll") \
      for (int s=0;s<4;s++){ \
        const unsigned int u = __float_as_uint(vv[s]); \
        const float lo = vv[s] - __uint_as_float(u & 0xFFFF0000u); \
        yh[(e4*4+s)*68 + j] = (unsigned short)(u>>16); \
        yl[(e4*4+s)*68 + j] = (unsigned short)rne_bf16(lo); \
      } \
    } \
  } }

  float4 pf[7];
  S3_LOAD(pf, 0);
  S3_WRITE(pf);

  #pragma unroll
  for (int t=0;t<8;t++){
    if (t < 7) S3_LOAD(pf, t+1);           // prefetch next tile into regs

    f32x16 acc0, acc1;
    #pragma unroll
    for (int i=0;i<16;i++){ acc0[i]=0.f; acc1[i]=0.f; }

    #pragma unroll
    for (int kk=0;kk<4;kk++){
      const int off = kk*16 + koff;
      const bf16x8 Bh = *reinterpret_cast<const bf16x8*>(&yh[r0*68 + off]);
      const bf16x8 Bl = *reinterpret_cast<const bf16x8*>(&yl[r0*68 + off]);
      acc0 = __builtin_amdgcn_mfma_f32_32x32x16_bf16(A0h[kk], Bh, acc0, 0,0,0);
      acc0 = __builtin_amdgcn_mfma_f32_32x32x16_bf16(A0h[kk], Bl, acc0, 0,0,0);
      acc0 = __builtin_amdgcn_mfma_f32_32x32x16_bf16(A0l[kk], Bh, acc0, 0,0,0);
      acc1 = __builtin_amdgcn_mfma_f32_32x32x16_bf16(A1h[kk], Bh, acc1, 0,0,0);
      acc1 = __builtin_amdgcn_mfma_f32_32x32x16_bf16(A1h[kk], Bl, acc1, 0,0,0);
      acc1 = __builtin_amdgcn_mfma_f32_32x32x16_bf16(A1l[kk], Bh, acc1, 0,0,0);
    }

    // store: col = chunk*1024 + (t*4+wave)*32 + (lane&31); row i from reg pattern
    {
      const int ecol = chunk*1024 + (t*4+wave)*32 + r0;
      const int c  = ecol >> 4;
      const int p1 = (ecol >> 2) & 3;
      const int p2 = ecol & 3;
      float* ob = ob_base + c*784 + p1*28 + p2;
      const int rbase = 4*(lane>>5);
      #pragma unroll
      for (int q=0;q<16;q++){
        const int i0 = (q&3) + 8*(q>>2) + rbase;       // 0..31
        ob[(i0/7)*112 + (i0%7)*4] = acc0[q];
        const int i1 = 32 + i0;
        if (i1 < 49) ob[(i1/7)*112 + (i1%7)*4] = acc1[q];
      }
    }

    if (t < 7) S3_WRITE(pf);               // in-wave DS order: writes land after reads above
  }
#undef S3_LOAD
#undef S3_WRITE
}

extern "C" void kernel_launch(void* const* d_in, const int* in_sizes, int n_in,
                              void* d_out, int out_size, void* d_ws, size_t ws_size,
                              hipStream_t stream) {
  const float* x = (const float*)d_in[0];
  float* out = (float*)d_out;
  float* ws  = (float*)d_ws;
  float* y1   = ws;                     // 25,690,112 floats (102.8 MB)
  float* wsA  = y1 + 25690112;          // 512*2500 = 1,280,000 floats
  float* wsWT = wsA + 512*2500;         // 128*2548 = 326,144 floats (W^T + I, padded 52)
  float* wsC  = wsWT + 128*2548;        // 128*49   -> total ~109.2 MB
  // overlay (dead before k_s1 writes wsA): temporal partials + per-seq W
  float* wsG  = wsA;                    // 784*16*44 = 551,936 floats
  float* wsWt = wsA + 551936;           // 784*72   =  56,448 floats (fits in wsA)
  hipLaunchKernelGGL(k_t1, dim3(1792), dim3(256), 0, stream, x, wsG);
  hipLaunchKernelGGL(k_t2, dim3(784),  dim3(64),  0, stream, wsG, wsWt);
  hipLaunchKernelGGL(k_t3, dim3(1792), dim3(256), 0, stream, x, wsWt, y1);
  hipLaunchKernelGGL(k_s1, dim3(512),  dim3(256), 0, stream, y1, wsA);
  hipLaunchKernelGGL(k_s2, dim3(128),  dim3(256), 0, stream, wsA, wsWT, wsC);
  hipLaunchKernelGGL(k_s3, dim3(512),  dim3(256), 0, stream, y1, wsWT, wsC, out);
}